// Round 2
// baseline (931.604 us; speedup 1.0000x reference)
//
#include <hip/hip_runtime.h>
#include <hip/hip_bf16.h>

typedef __bf16 bf16_t;
typedef bf16_t bf16x2 __attribute__((ext_vector_type(2)));
typedef bf16_t bf16x4 __attribute__((ext_vector_type(4)));
typedef bf16_t bf16x8 __attribute__((ext_vector_type(8)));
typedef float f32x2 __attribute__((ext_vector_type(2)));
typedef float f32x4 __attribute__((ext_vector_type(4)));

static constexpr int NCn = 100000;
static constexpr int NPn = 50000;
static constexpr int NE  = 500000;

// Dual-dtype input load: inputs may be fp32 or bf16 (runtime-detected flag).
__device__ __forceinline__ float ldin(const void* p, size_t i, int fp32) {
    return fp32 ? ((const float*)p)[i] : (float)((const bf16_t*)p)[i];
}

__global__ __launch_bounds__(64) void detect_dtype(const void* x, int* flag) {
    const bf16_t* xb = (const bf16_t*)x;
    int lane = threadIdx.x;
    int bad = 0;
    for (int i = lane; i < 512; i += 64) {
        float v = (float)xb[i];
        if (!(v > -1e4f && v < 1e4f)) bad = 1;
    }
    unsigned long long m = __ballot(bad);
    if (lane == 0) flag[0] = (m != 0ull) ? 1 : 0;
}

// ---- tiny utility kernels (replace hipMemsetAsync / hipMemcpyAsync) ---------
__global__ __launch_bounds__(256) void zero_int(int* __restrict__ p, int n) {
    int i = blockIdx.x * 256 + threadIdx.x;
    if (i < n) p[i] = 0;
}
__global__ __launch_bounds__(256) void copy_int(const int* __restrict__ s,
                                                int* __restrict__ d, int n) {
    int i = blockIdx.x * 256 + threadIdx.x;
    if (i < n) d[i] = s[i];
}

// Fold dst-projection against attention vector: V[k,h] = sum_c W[k,h*C+c]*att[h,c]
__global__ __launch_bounds__(256) void prep_V(const int* __restrict__ flag,
                                              const void* w1bd, const void* a1bd,
                                              const void* w1rd, const void* a1rd,
                                              const void* w2bd, const void* a2bd,
                                              const void* w2rd, const void* a2rd,
                                              float* V1bd, float* V1rd,
                                              float* V2bd, float* V2rd) {
    int fp32 = flag[0];
    int t = threadIdx.x;
    for (int idx = t; idx < 256; idx += 256) {          // V1bd: k<128, h<2
        int k = idx >> 1, h = idx & 1;
        float s = 0.f;
        for (int c = 0; c < 64; ++c)
            s += ldin(w1bd, (size_t)k * 128 + h * 64 + c, fp32) * ldin(a1bd, h * 64 + c, fp32);
        V1bd[k * 2 + h] = s;
    }
    for (int idx = t; idx < 512; idx += 256) {          // V1rd: k<256, h<2
        int k = idx >> 1, h = idx & 1;
        float s = 0.f;
        for (int c = 0; c < 64; ++c)
            s += ldin(w1rd, (size_t)k * 128 + h * 64 + c, fp32) * ldin(a1rd, h * 64 + c, fp32);
        V1rd[k * 2 + h] = s;
    }
    for (int k = t; k < 128; k += 256) {                // V2bd
        float s = 0.f;
        for (int c = 0; c < 64; ++c)
            s += ldin(w2bd, (size_t)k * 64 + c, fp32) * ldin(a2bd, c, fp32);
        V2bd[k] = s;
    }
    for (int k = t; k < 128; k += 256) {                // V2rd
        float s = 0.f;
        for (int c = 0; c < 64; ++c)
            s += ldin(w2rd, (size_t)k * 64 + c, fp32) * ldin(a2rd, c, fp32);
        V2rd[k] = s;
    }
}

// Transpose + convert weight W[K][N] (input dtype) -> Wt[N][K] bf16.
__global__ __launch_bounds__(256) void prep_w(const void* __restrict__ W,
                                              bf16_t* __restrict__ Wt,
                                              int N, int ks,
                                              const int* __restrict__ flag) {
    int fp32 = flag[0];
    int idx = blockIdx.x * 256 + threadIdx.x;
    int K = 1 << ks;
    int n = idx >> ks, k = idx & (K - 1);
    if (n < N) Wt[idx] = (bf16_t)ldin(W, (size_t)k * N + n, fp32);
}

// Convert X[M][K] (flag dtype) -> bf16, fused with ad[m,h] = X[m,:] @ V[:,h].
template<int K>
__global__ __launch_bounds__(256) void cvt_rows(const void* __restrict__ X,
                                                bf16_t* __restrict__ Xb,
                                                const float* __restrict__ V,
                                                float* __restrict__ ad,
                                                int M, const int* __restrict__ flag) {
    constexpr int EPL = K / 64;
    int fp32 = flag[0];
    int wid = (blockIdx.x * 256 + threadIdx.x) >> 6;
    int lane = threadIdx.x & 63;
    if (wid >= M) return;
    size_t base = (size_t)wid * K + lane * EPL;
    float x[EPL];
    if constexpr (EPL == 4) {
        if (fp32) { f32x4 t = *(const f32x4*)((const float*)X + base);
#pragma unroll
            for (int j = 0; j < 4; ++j) x[j] = t[j];
        } else { bf16x4 t = *(const bf16x4*)((const bf16_t*)X + base);
#pragma unroll
            for (int j = 0; j < 4; ++j) x[j] = (float)t[j];
        }
        bf16x4 o;
#pragma unroll
        for (int j = 0; j < 4; ++j) o[j] = (bf16_t)x[j];
        *(bf16x4*)(Xb + base) = o;
    } else {
        if (fp32) { f32x2 t = *(const f32x2*)((const float*)X + base);
#pragma unroll
            for (int j = 0; j < 2; ++j) x[j] = t[j];
        } else { bf16x2 t = *(const bf16x2*)((const bf16_t*)X + base);
#pragma unroll
            for (int j = 0; j < 2; ++j) x[j] = (float)t[j];
        }
        bf16x2 o;
#pragma unroll
        for (int j = 0; j < 2; ++j) o[j] = (bf16_t)x[j];
        *(bf16x2*)(Xb + base) = o;
    }
    float a0 = 0.f, a1 = 0.f;
#pragma unroll
    for (int j = 0; j < EPL; ++j) {
        int k = lane * EPL + j;
        a0 += x[j] * V[k * 2];
        a1 += x[j] * V[k * 2 + 1];
    }
    for (int off = 32; off; off >>= 1) {
        a0 += __shfl_down(a0, off);
        a1 += __shfl_down(a1, off);
    }
    if (lane == 0) { ad[(size_t)wid * 2] = a0; ad[(size_t)wid * 2 + 1] = a1; }
}

// ---------------- CSR build: histogram -> hierarchical scan -> scatter --------
__global__ __launch_bounds__(256) void hist_k(const int* __restrict__ dst,
                                              int* __restrict__ cnt, int E) {
    int e = blockIdx.x * 256 + threadIdx.x;
    if (e < E) atomicAdd(&cnt[dst[e]], 1);
}

__global__ __launch_bounds__(256) void scan_blocks(const int* __restrict__ cnt,
                                                   int* __restrict__ rs,
                                                   int* __restrict__ bsum, int N) {
    int t = threadIdx.x, b = blockIdx.x;
    int base = b * 1024 + t * 4;
    int c[4];
#pragma unroll
    for (int k = 0; k < 4; ++k) { int i = base + k; c[k] = (i < N) ? cnt[i] : 0; }
    int tsum = c[0] + c[1] + c[2] + c[3];
    __shared__ int sd[256];
    sd[t] = tsum;
    __syncthreads();
    for (int off = 1; off < 256; off <<= 1) {
        int x = (t >= off) ? sd[t - off] : 0;
        __syncthreads();
        sd[t] += x;
        __syncthreads();
    }
    int run = sd[t] - tsum;
#pragma unroll
    for (int k = 0; k < 4; ++k) { int i = base + k; if (i < N) rs[i] = run; run += c[k]; }
    if (t == 255) bsum[b] = sd[255];
}

__global__ __launch_bounds__(128) void scan_bsum(int* bsum, int nb) {
    int t = threadIdx.x;
    __shared__ int sd[128];
    int v = (t < nb) ? bsum[t] : 0;
    sd[t] = v;
    __syncthreads();
    for (int off = 1; off < 128; off <<= 1) {
        int x = (t >= off) ? sd[t - off] : 0;
        __syncthreads();
        sd[t] += x;
        __syncthreads();
    }
    if (t < nb) bsum[t] = sd[t] - v;
}

__global__ __launch_bounds__(256) void scan_add(int* __restrict__ rs,
                                                const int* __restrict__ bsum,
                                                int N, int E) {
    int i = blockIdx.x * 256 + threadIdx.x;
    if (i < N) rs[i] += bsum[i >> 10];
    if (i == 0) rs[N] = E;
}

__global__ __launch_bounds__(256) void scatter_k(const int* __restrict__ dst,
                                                 const int* __restrict__ nbr,
                                                 int* __restrict__ cur,
                                                 int* __restrict__ srcs,
                                                 int* __restrict__ dsts, int E) {
    int e = blockIdx.x * 256 + threadIdx.x;
    if (e >= E) return;
    int d = dst[e];
    int pos = atomicAdd(&cur[d], 1);
    srcs[pos] = nbr[e];
    dsts[pos] = d;
}

// ---------------- LDS-free GEMM: C[M,N] = A[M,K] @ Wt[N,K]^T, all bf16 -------
template<int K>
__global__ __launch_bounds__(256) void gemm_nl(const bf16_t* __restrict__ A,
                                               const bf16_t* __restrict__ Wt,
                                               bf16_t* __restrict__ C,
                                               int M, int N) {
    const int w = threadIdx.x >> 6;
    const int lane = threadIdx.x & 63;
    const int lm = lane & 15;
    const int lq = lane >> 4;
    const int n0 = blockIdx.y * 64;
    const int r0 = blockIdx.x * 128 + w * 32;
    int ra0 = r0 + lm;       if (ra0 > M - 1) ra0 = M - 1;
    int ra1 = r0 + 16 + lm;  if (ra1 > M - 1) ra1 = M - 1;
    const bf16_t* A0 = A + (size_t)ra0 * K + lq * 8;
    const bf16_t* A1 = A + (size_t)ra1 * K + lq * 8;
    const bf16_t* B0 = Wt + (size_t)(n0 + lm) * K + lq * 8;
    f32x4 acc[2][4] = {};
#pragma unroll
    for (int kt = 0; kt < K / 32; ++kt) {
        bf16x8 a0 = *(const bf16x8*)(A0 + kt * 32);
        bf16x8 a1 = *(const bf16x8*)(A1 + kt * 32);
#pragma unroll
        for (int nt = 0; nt < 4; ++nt) {
            bf16x8 b = *(const bf16x8*)(B0 + (size_t)nt * 16 * K + kt * 32);
            acc[0][nt] = __builtin_amdgcn_mfma_f32_16x16x32_bf16(a0, b, acc[0][nt], 0, 0, 0);
            acc[1][nt] = __builtin_amdgcn_mfma_f32_16x16x32_bf16(a1, b, acc[1][nt], 0, 0, 0);
        }
    }
#pragma unroll
    for (int rt = 0; rt < 2; ++rt) {
        const int crow0 = r0 + rt * 16 + lq * 4;
#pragma unroll
        for (int nt = 0; nt < 4; ++nt) {
            int col = n0 + nt * 16 + lm;
#pragma unroll
            for (int i = 0; i < 4; ++i) {
                int r = crow0 + i;
                if (r < M) C[(size_t)r * N + col] = (bf16_t)acc[rt][nt][i];
            }
        }
    }
}

// ---------------- a_s = sum_c h[n,h,c]*att[h,c] : one wave per node ----------
__global__ __launch_bounds__(256) void att_dot(const bf16_t* __restrict__ Hb,
                                               const void* __restrict__ att,
                                               float* __restrict__ out,
                                               int Nn, int HD, int H,
                                               const int* __restrict__ flag) {
    int fp32 = flag[0];
    int wid = (blockIdx.x * 256 + threadIdx.x) >> 6;
    int lane = threadIdx.x & 63;
    if (wid >= Nn) return;
    const bf16_t* hp = Hb + (size_t)wid * HD;
    float p0 = (float)hp[lane] * ldin(att, lane, fp32);
    float p1 = 0.f;
    if (HD > 64) p1 = (float)hp[64 + lane] * ldin(att, 64 + lane, fp32);
    for (int off = 32; off; off >>= 1) {
        p0 += __shfl_down(p0, off);
        p1 += __shfl_down(p1, off);
    }
    if (lane == 0) {
        out[(size_t)wid * H] = p0;
        if (H == 2) out[(size_t)wid * H + 1] = p1;
    }
}

// ---------------- edge-parallel exp(leaky(as[src]+ad[dst])) in CSR order -----
// 500k independent threads; gathers hit L2/L3 (tables < 1 MB). Removes all
// exp/leaky VALU and as_/ad_ gathers from the wave-serial aggregate loop.
template<int H>
__global__ __launch_bounds__(256) void edge_ex(const int* __restrict__ srcs,
                                               const int* __restrict__ dsts,
                                               const float* __restrict__ as_,
                                               const float* __restrict__ ad_,
                                               float* __restrict__ ex, int E) {
    int i = blockIdx.x * 256 + threadIdx.x;
    if (i >= E) return;
    int s = srcs[i], d = dsts[i];
    if constexpr (H == 2) {
        f32x2 a = *(const f32x2*)(as_ + 2 * (size_t)s);
        f32x2 b = *(const f32x2*)(ad_ + 2 * (size_t)d);
        float v0 = a[0] + b[0]; v0 = v0 > 0.f ? v0 : 0.2f * v0;
        float v1 = a[1] + b[1]; v1 = v1 > 0.f ? v1 : 0.2f * v1;
        f32x2 o;
        o[0] = __expf(fminf(v0, 60.f));
        o[1] = __expf(fminf(v1, 60.f));
        *(f32x2*)(ex + 2 * (size_t)i) = o;
    } else {
        float v = as_[s] + ad_[d];
        v = v > 0.f ? v : 0.2f * v;
        ex[i] = __expf(fminf(v, 60.f));
    }
}

// ---------------- fused segment-softmax + aggregate --------------------------
// ex[] precomputed in CSR order -> den pass is one coalesced load + reduce;
// accumulate processes 4 edges/iteration (quarter-waves), ALL operands loaded
// directly (no cross-lane ops in the loop) so iterations pipeline freely.
// MODE 0 (layer1, HD=128): relu + bf16 out + fused ad2 = relu(out) . V2.
// MODE 1 (layer2, HD=64): final output, dtype per flag, no relu.
template<int HD, int MODE>
__global__ __launch_bounds__(256) void aggregate(const int* __restrict__ rs,
                                                 const int* __restrict__ srcs,
                                                 const float* __restrict__ ex,
                                                 const bf16_t* __restrict__ Hm,
                                                 const void* __restrict__ bias,
                                                 void* __restrict__ outb, size_t obase,
                                                 const float* __restrict__ V2,
                                                 float* __restrict__ ad2,
                                                 int Nd, const int* __restrict__ flag) {
    constexpr int NH = HD / 64;       // heads: 2 (layer1) or 1 (layer2)
    constexpr int CPL = HD / 16;      // channels per lane: 8 or 4
    int wid = (blockIdx.x * 256 + threadIdx.x) >> 6;
    int lane = threadIdx.x & 63;
    if (wid >= Nd) return;
    int start = rs[wid], end = rs[wid + 1];
    int deg = end - start;
    int fp32 = flag[0];

    // ---- denominators: coalesced read of precomputed ex ----
    float den0 = 0.f, den1 = 0.f;
    if (deg <= 64) {
        if (lane < deg) {
            if (NH == 2) {
                f32x2 e = *(const f32x2*)(ex + 2 * (size_t)(start + lane));
                den0 = e[0]; den1 = e[1];
            } else den0 = ex[start + lane];
        }
    } else {
        for (int i = lane; i < deg; i += 64) {
            if (NH == 2) {
                f32x2 e = *(const f32x2*)(ex + 2 * (size_t)(start + i));
                den0 += e[0]; den1 += e[1];
            } else den0 += ex[start + i];
        }
    }
    for (int off = 32; off; off >>= 1) {
        den0 += __shfl_down(den0, off);
        if (NH == 2) den1 += __shfl_down(den1, off);
    }
    den0 = __shfl(den0, 0);
    float inv0 = 1.f / (den0 + 1e-16f), inv1 = 0.f;
    if (NH == 2) { den1 = __shfl(den1, 0); inv1 = 1.f / (den1 + 1e-16f); }

    // ---- accumulate: 4 edges per iteration, direct loads only ----
    const int q = lane >> 4;
    const int l15 = lane & 15;
    float acc[CPL];
#pragma unroll
    for (int i = 0; i < CPL; ++i) acc[i] = 0.f;
#pragma unroll 2
    for (int j0 = 0; j0 < deg; j0 += 4) {
        int jj = j0 + q;
        if (jj < deg) {
            int sj = srcs[start + jj];
            float w;
            if (NH == 2) {
                f32x2 e = *(const f32x2*)(ex + 2 * (size_t)(start + jj));
                w = (l15 >= 8) ? e[1] * inv1 : e[0] * inv0;
            } else {
                w = ex[start + jj] * inv0;
            }
            if constexpr (HD == 128) {
                bf16x8 hv = *(const bf16x8*)(Hm + (size_t)sj * 128 + l15 * 8);
#pragma unroll
                for (int i = 0; i < 8; ++i) acc[i] += (float)hv[i] * w;
            } else {
                bf16x4 hv = *(const bf16x4*)(Hm + (size_t)sj * 64 + l15 * 4);
#pragma unroll
                for (int i = 0; i < 4; ++i) acc[i] += (float)hv[i] * w;
            }
        }
    }
    // combine quarter partials -> every lane has totals for its l15 group
#pragma unroll
    for (int i = 0; i < CPL; ++i) {
        acc[i] += __shfl_xor(acc[i], 16);
        acc[i] += __shfl_xor(acc[i], 32);
    }
    const int c0 = l15 * CPL;
    if constexpr (MODE == 0) {
        float o[CPL];
        float pp = 0.f;
#pragma unroll
        for (int i = 0; i < CPL; ++i) {
            o[i] = fmaxf(acc[i] + ldin(bias, c0 + i, fp32), 0.f);
            pp += o[i] * V2[c0 + i];
        }
        if (lane < 16) {
            bf16x8 ov;
#pragma unroll
            for (int i = 0; i < 8; ++i) ov[i] = (bf16_t)o[i];
            *(bf16x8*)((bf16_t*)outb + (size_t)wid * 128 + c0) = ov;
        }
        for (int off = 8; off; off >>= 1) pp += __shfl_down(pp, off);
        if (lane == 0) ad2[wid] = pp;
    } else {
        if (lane < 16) {
            if (fp32) {
                f32x4 ov;
#pragma unroll
                for (int i = 0; i < 4; ++i) ov[i] = acc[i] + ldin(bias, c0 + i, fp32);
                *(f32x4*)((float*)outb + obase + (size_t)wid * 64 + c0) = ov;
            } else {
                bf16x4 ov;
#pragma unroll
                for (int i = 0; i < 4; ++i) ov[i] = (bf16_t)(acc[i] + ldin(bias, c0 + i, fp32));
                *(bf16x4*)((bf16_t*)outb + obase + (size_t)wid * 64 + c0) = ov;
            }
        }
    }
}

extern "C" void kernel_launch(void* const* d_in, const int* in_sizes, int n_in,
                              void* d_out, int out_size, void* d_ws, size_t ws_size,
                              hipStream_t stream) {
    const void* xc = d_in[0];
    const void* xp = d_in[1];
    const int* esrc = (const int*)d_in[2];   // customer ids
    const int* edst = (const int*)d_in[3];   // product ids
    const void* w1b_src = d_in[4];
    const void* w1b_dst = d_in[5];
    const void* a1b_src = d_in[6];
    const void* a1b_dst = d_in[7];
    const void* b1b     = d_in[8];
    const void* w1r_src = d_in[9];
    const void* w1r_dst = d_in[10];
    const void* a1r_src = d_in[11];
    const void* a1r_dst = d_in[12];
    const void* b1r     = d_in[13];
    const void* w2b_src = d_in[14];
    const void* w2b_dst = d_in[15];
    const void* a2b_src = d_in[16];
    const void* a2b_dst = d_in[17];
    const void* b2b     = d_in[18];
    const void* w2r_src = d_in[19];
    const void* w2r_dst = d_in[20];
    const void* a2r_src = d_in[21];
    const void* a2r_dst = d_in[22];
    const void* b2r     = d_in[23];

    // -------- workspace layout: NO aliasing (~180 MB, ws proven >= 199 MB) ----
    char* p = (char*)d_ws;
    auto alloc = [&](size_t nbytes) {
        char* r = p;
        p += (nbytes + 255) & ~(size_t)255;
        return r;
    };
    int* flag   = (int*)alloc(256);
    float* V1bd = (float*)alloc(256 * 4);
    float* V1rd = (float*)alloc(512 * 4);
    float* V2bd = (float*)alloc(128 * 4);
    float* V2rd = (float*)alloc(128 * 4);
    bf16_t* Wt1b = (bf16_t*)alloc(128 * 256 * 2);
    bf16_t* Wt1r = (bf16_t*)alloc(128 * 128 * 2);
    bf16_t* Wt2b = (bf16_t*)alloc(64 * 128 * 2);
    bf16_t* Wt2r = (bf16_t*)alloc(64 * 128 * 2);
    float* as_s = (float*)alloc((size_t)NCn * 2 * 4);
    float* ad_b = (float*)alloc((size_t)NPn * 2 * 4);
    float* ad_r = (float*)alloc((size_t)NCn * 2 * 4);
    float* ad2_b = (float*)alloc((size_t)NPn * 4);
    float* ad2_r = (float*)alloc((size_t)NCn * 4);
    int* rsB    = (int*)alloc((size_t)(NPn + 1) * 4);
    int* rsR    = (int*)alloc((size_t)(NCn + 1) * 4);
    int* srcsB  = (int*)alloc((size_t)NE * 4);
    int* srcsR  = (int*)alloc((size_t)NE * 4);
    int* dstsB  = (int*)alloc((size_t)NE * 4);
    int* dstsR  = (int*)alloc((size_t)NE * 4);
    float* exB  = (float*)alloc((size_t)NE * 2 * 4);
    float* exR  = (float*)alloc((size_t)NE * 2 * 4);
    int* cntB   = (int*)alloc((size_t)NPn * 4);
    int* cntR   = (int*)alloc((size_t)NCn * 4);
    int* bsum   = (int*)alloc(128 * 4);
    bf16_t* xcb = (bf16_t*)alloc((size_t)NCn * 256 * 2);
    bf16_t* xpb = (bf16_t*)alloc((size_t)NPn * 128 * 2);
    bf16_t* Hc  = (bf16_t*)alloc((size_t)NCn * 128 * 2);
    bf16_t* Hp  = (bf16_t*)alloc((size_t)NPn * 128 * 2);
    bf16_t* c1  = (bf16_t*)alloc((size_t)NCn * 128 * 2);
    bf16_t* p1  = (bf16_t*)alloc((size_t)NPn * 128 * 2);
    bf16_t* Hc2 = (bf16_t*)alloc((size_t)NCn * 64 * 2);
    bf16_t* Hp2 = (bf16_t*)alloc((size_t)NPn * 64 * 2);

    const dim3 blk(256);
    const int gE = (NE + 255) / 256;
    const int sbP = (NPn + 1023) / 1024;
    const int sbR = (NCn + 1023) / 1024;
    const int gmC = (NCn + 127) / 128;
    const int gmP = (NPn + 127) / 128;
    const int gNP = (NPn + 255) / 256;
    const int gNC = (NCn + 255) / 256;

    detect_dtype<<<1, 64, 0, stream>>>(xc, flag);
    prep_V<<<1, 256, 0, stream>>>(flag, w1b_dst, a1b_dst, w1r_dst, a1r_dst,
                                  w2b_dst, a2b_dst, w2r_dst, a2r_dst,
                                  V1bd, V1rd, V2bd, V2rd);
    prep_w<<<128, blk, 0, stream>>>(w1b_src, Wt1b, 128, 8, flag);
    prep_w<<<64,  blk, 0, stream>>>(w1r_src, Wt1r, 128, 7, flag);
    prep_w<<<32,  blk, 0, stream>>>(w2b_src, Wt2b, 64, 7, flag);
    prep_w<<<32,  blk, 0, stream>>>(w2r_src, Wt2r, 64, 7, flag);

    // -------- CSR build dir b (dst = product) --------
    zero_int<<<gNP, blk, 0, stream>>>(cntB, NPn);
    hist_k<<<gE, blk, 0, stream>>>(edst, cntB, NE);
    scan_blocks<<<sbP, blk, 0, stream>>>(cntB, rsB, bsum, NPn);
    scan_bsum<<<1, 128, 0, stream>>>(bsum, sbP);
    scan_add<<<gNP + 1, blk, 0, stream>>>(rsB, bsum, NPn, NE);
    copy_int<<<gNP, blk, 0, stream>>>(rsB, cntB, NPn);
    scatter_k<<<gE, blk, 0, stream>>>(edst, esrc, cntB, srcsB, dstsB, NE);

    // -------- CSR build dir r (dst = customer) --------
    zero_int<<<gNC, blk, 0, stream>>>(cntR, NCn);
    hist_k<<<gE, blk, 0, stream>>>(esrc, cntR, NE);
    scan_blocks<<<sbR, blk, 0, stream>>>(cntR, rsR, bsum, NCn);
    scan_bsum<<<1, 128, 0, stream>>>(bsum, sbR);
    scan_add<<<gNC + 1, blk, 0, stream>>>(rsR, bsum, NCn, NE);
    copy_int<<<gNC, blk, 0, stream>>>(rsR, cntR, NCn);
    scatter_k<<<gE, blk, 0, stream>>>(esrc, edst, cntR, srcsR, dstsR, NE);

    // -------- convert inputs to bf16 + fused L1 dst scores --------
    cvt_rows<256><<<(NCn + 3) / 4, blk, 0, stream>>>(xc, xcb, V1rd, ad_r, NCn, flag);
    cvt_rows<128><<<(NPn + 3) / 4, blk, 0, stream>>>(xp, xpb, V1bd, ad_b, NPn, flag);

    // -------- layer 1 src projections --------
    gemm_nl<256><<<dim3(gmC, 2), blk, 0, stream>>>(xcb, Wt1b, Hc, NCn, 128);
    gemm_nl<128><<<dim3(gmP, 2), blk, 0, stream>>>(xpb, Wt1r, Hp, NPn, 128);

    // ---- L1 dir b (customer -> product) -> p1 (+ fused ad2_b = p1.V2bd) ----
    att_dot<<<(NCn + 3) / 4, blk, 0, stream>>>(Hc, a1b_src, as_s, NCn, 128, 2, flag);
    edge_ex<2><<<gE, blk, 0, stream>>>(srcsB, dstsB, as_s, ad_b, exB, NE);
    aggregate<128, 0><<<(NPn + 3) / 4, blk, 0, stream>>>(rsB, srcsB, exB, Hc, b1b, p1, 0, V2bd, ad2_b, NPn, flag);

    // ---- L1 dir r (product -> customer) -> c1 (+ fused ad2_r = c1.V2rd) ----
    att_dot<<<(NPn + 3) / 4, blk, 0, stream>>>(Hp, a1r_src, as_s, NPn, 128, 2, flag);
    edge_ex<2><<<gE, blk, 0, stream>>>(srcsR, dstsR, as_s, ad_r, exR, NE);
    aggregate<128, 0><<<(NCn + 3) / 4, blk, 0, stream>>>(rsR, srcsR, exR, Hp, b1r, c1, 0, V2rd, ad2_r, NCn, flag);

    // -------- layer 2 src projections --------
    gemm_nl<128><<<dim3(gmC, 1), blk, 0, stream>>>(c1, Wt2b, Hc2, NCn, 64);
    gemm_nl<128><<<dim3(gmP, 1), blk, 0, stream>>>(p1, Wt2r, Hp2, NPn, 64);

    // ---- L2 dir b -> p2 (second half of d_out) ----
    att_dot<<<(NCn + 3) / 4, blk, 0, stream>>>(Hc2, a2b_src, as_s, NCn, 64, 1, flag);
    edge_ex<1><<<gE, blk, 0, stream>>>(srcsB, dstsB, as_s, ad2_b, exB, NE);
    aggregate<64, 1><<<(NPn + 3) / 4, blk, 0, stream>>>(rsB, srcsB, exB, Hc2, b2b, d_out, (size_t)NCn * 64, nullptr, nullptr, NPn, flag);

    // ---- L2 dir r -> c2 (first half of d_out) ----
    att_dot<<<(NPn + 3) / 4, blk, 0, stream>>>(Hp2, a2r_src, as_s, NPn, 64, 1, flag);
    edge_ex<1><<<gE, blk, 0, stream>>>(srcsR, dstsR, as_s, ad2_r, exR, NE);
    aggregate<64, 1><<<(NCn + 3) / 4, blk, 0, stream>>>(rsR, srcsR, exR, Hp2, b2r, d_out, 0, nullptr, nullptr, NCn, flag);
}

// Round 3
// 717.283 us; speedup vs baseline: 1.2988x; 1.2988x over previous
//
#include <hip/hip_runtime.h>
#include <hip/hip_bf16.h>

typedef __bf16 bf16_t;
typedef bf16_t bf16x2 __attribute__((ext_vector_type(2)));
typedef bf16_t bf16x4 __attribute__((ext_vector_type(4)));
typedef bf16_t bf16x8 __attribute__((ext_vector_type(8)));
typedef float f32x2 __attribute__((ext_vector_type(2)));
typedef float f32x4 __attribute__((ext_vector_type(4)));

static constexpr int NCn = 100000;
static constexpr int NPn = 50000;
static constexpr int NE  = 500000;

// Dual-dtype input load: inputs may be fp32 or bf16 (runtime-detected flag).
__device__ __forceinline__ float ldin(const void* p, size_t i, int fp32) {
    return fp32 ? ((const float*)p)[i] : (float)((const bf16_t*)p)[i];
}

__global__ __launch_bounds__(64) void detect_dtype(const void* x, int* flag) {
    const bf16_t* xb = (const bf16_t*)x;
    int lane = threadIdx.x;
    int bad = 0;
    for (int i = lane; i < 512; i += 64) {
        float v = (float)xb[i];
        if (!(v > -1e4f && v < 1e4f)) bad = 1;
    }
    unsigned long long m = __ballot(bad);
    if (lane == 0) flag[0] = (m != 0ull) ? 1 : 0;
}

// ---- tiny utility kernels (replace hipMemsetAsync / hipMemcpyAsync) ---------
__global__ __launch_bounds__(256) void zero_int(int* __restrict__ p, int n) {
    int i = blockIdx.x * 256 + threadIdx.x;
    if (i < n) p[i] = 0;
}
__global__ __launch_bounds__(256) void copy_int(const int* __restrict__ s,
                                                int* __restrict__ d, int n) {
    int i = blockIdx.x * 256 + threadIdx.x;
    if (i < n) d[i] = s[i];
}

// Fold dst-projection against attention vector: V[k,h] = sum_c W[k,h*C+c]*att[h,c]
__global__ __launch_bounds__(256) void prep_V(const int* __restrict__ flag,
                                              const void* w1bd, const void* a1bd,
                                              const void* w1rd, const void* a1rd,
                                              const void* w2bd, const void* a2bd,
                                              const void* w2rd, const void* a2rd,
                                              float* V1bd, float* V1rd,
                                              float* V2bd, float* V2rd) {
    int fp32 = flag[0];
    int t = threadIdx.x;
    for (int idx = t; idx < 256; idx += 256) {          // V1bd: k<128, h<2
        int k = idx >> 1, h = idx & 1;
        float s = 0.f;
        for (int c = 0; c < 64; ++c)
            s += ldin(w1bd, (size_t)k * 128 + h * 64 + c, fp32) * ldin(a1bd, h * 64 + c, fp32);
        V1bd[k * 2 + h] = s;
    }
    for (int idx = t; idx < 512; idx += 256) {          // V1rd: k<256, h<2
        int k = idx >> 1, h = idx & 1;
        float s = 0.f;
        for (int c = 0; c < 64; ++c)
            s += ldin(w1rd, (size_t)k * 128 + h * 64 + c, fp32) * ldin(a1rd, h * 64 + c, fp32);
        V1rd[k * 2 + h] = s;
    }
    for (int k = t; k < 128; k += 256) {                // V2bd
        float s = 0.f;
        for (int c = 0; c < 64; ++c)
            s += ldin(w2bd, (size_t)k * 64 + c, fp32) * ldin(a2bd, c, fp32);
        V2bd[k] = s;
    }
    for (int k = t; k < 128; k += 256) {                // V2rd
        float s = 0.f;
        for (int c = 0; c < 64; ++c)
            s += ldin(w2rd, (size_t)k * 64 + c, fp32) * ldin(a2rd, c, fp32);
        V2rd[k] = s;
    }
}

// Transpose + convert weight W[K][N] (input dtype) -> Wt[N][K] bf16.
__global__ __launch_bounds__(256) void prep_w(const void* __restrict__ W,
                                              bf16_t* __restrict__ Wt,
                                              int N, int ks,
                                              const int* __restrict__ flag) {
    int fp32 = flag[0];
    int idx = blockIdx.x * 256 + threadIdx.x;
    int K = 1 << ks;
    int n = idx >> ks, k = idx & (K - 1);
    if (n < N) Wt[idx] = (bf16_t)ldin(W, (size_t)k * N + n, fp32);
}

// Convert X[M][K] (flag dtype) -> bf16, fused with ad[m,h] = X[m,:] @ V[:,h].
template<int K>
__global__ __launch_bounds__(256) void cvt_rows(const void* __restrict__ X,
                                                bf16_t* __restrict__ Xb,
                                                const float* __restrict__ V,
                                                float* __restrict__ ad,
                                                int M, const int* __restrict__ flag) {
    constexpr int EPL = K / 64;
    int fp32 = flag[0];
    int wid = (blockIdx.x * 256 + threadIdx.x) >> 6;
    int lane = threadIdx.x & 63;
    if (wid >= M) return;
    size_t base = (size_t)wid * K + lane * EPL;
    float x[EPL];
    if constexpr (EPL == 4) {
        if (fp32) { f32x4 t = *(const f32x4*)((const float*)X + base);
#pragma unroll
            for (int j = 0; j < 4; ++j) x[j] = t[j];
        } else { bf16x4 t = *(const bf16x4*)((const bf16_t*)X + base);
#pragma unroll
            for (int j = 0; j < 4; ++j) x[j] = (float)t[j];
        }
        bf16x4 o;
#pragma unroll
        for (int j = 0; j < 4; ++j) o[j] = (bf16_t)x[j];
        *(bf16x4*)(Xb + base) = o;
    } else {
        if (fp32) { f32x2 t = *(const f32x2*)((const float*)X + base);
#pragma unroll
            for (int j = 0; j < 2; ++j) x[j] = t[j];
        } else { bf16x2 t = *(const bf16x2*)((const bf16_t*)X + base);
#pragma unroll
            for (int j = 0; j < 2; ++j) x[j] = (float)t[j];
        }
        bf16x2 o;
#pragma unroll
        for (int j = 0; j < 2; ++j) o[j] = (bf16_t)x[j];
        *(bf16x2*)(Xb + base) = o;
    }
    float a0 = 0.f, a1 = 0.f;
#pragma unroll
    for (int j = 0; j < EPL; ++j) {
        int k = lane * EPL + j;
        a0 += x[j] * V[k * 2];
        a1 += x[j] * V[k * 2 + 1];
    }
    for (int off = 32; off; off >>= 1) {
        a0 += __shfl_down(a0, off);
        a1 += __shfl_down(a1, off);
    }
    if (lane == 0) { ad[(size_t)wid * 2] = a0; ad[(size_t)wid * 2 + 1] = a1; }
}

// ---------------- CSR build: histogram -> hierarchical scan -> scatter --------
__global__ __launch_bounds__(256) void hist_k(const int* __restrict__ dst,
                                              int* __restrict__ cnt, int E) {
    int e = blockIdx.x * 256 + threadIdx.x;
    if (e < E) atomicAdd(&cnt[dst[e]], 1);
}

__global__ __launch_bounds__(256) void scan_blocks(const int* __restrict__ cnt,
                                                   int* __restrict__ rs,
                                                   int* __restrict__ bsum, int N) {
    int t = threadIdx.x, b = blockIdx.x;
    int base = b * 1024 + t * 4;
    int c[4];
#pragma unroll
    for (int k = 0; k < 4; ++k) { int i = base + k; c[k] = (i < N) ? cnt[i] : 0; }
    int tsum = c[0] + c[1] + c[2] + c[3];
    __shared__ int sd[256];
    sd[t] = tsum;
    __syncthreads();
    for (int off = 1; off < 256; off <<= 1) {
        int x = (t >= off) ? sd[t - off] : 0;
        __syncthreads();
        sd[t] += x;
        __syncthreads();
    }
    int run = sd[t] - tsum;
#pragma unroll
    for (int k = 0; k < 4; ++k) { int i = base + k; if (i < N) rs[i] = run; run += c[k]; }
    if (t == 255) bsum[b] = sd[255];
}

__global__ __launch_bounds__(128) void scan_bsum(int* bsum, int nb) {
    int t = threadIdx.x;
    __shared__ int sd[128];
    int v = (t < nb) ? bsum[t] : 0;
    sd[t] = v;
    __syncthreads();
    for (int off = 1; off < 128; off <<= 1) {
        int x = (t >= off) ? sd[t - off] : 0;
        __syncthreads();
        sd[t] += x;
        __syncthreads();
    }
    if (t < nb) bsum[t] = sd[t] - v;
}

__global__ __launch_bounds__(256) void scan_add(int* __restrict__ rs,
                                                const int* __restrict__ bsum,
                                                int N, int E) {
    int i = blockIdx.x * 256 + threadIdx.x;
    if (i < N) rs[i] += bsum[i >> 10];
    if (i == 0) rs[N] = E;
}

__global__ __launch_bounds__(256) void scatter_k(const int* __restrict__ dst,
                                                 const int* __restrict__ nbr,
                                                 int* __restrict__ cur,
                                                 int* __restrict__ srcs,
                                                 int* __restrict__ dsts, int E) {
    int e = blockIdx.x * 256 + threadIdx.x;
    if (e >= E) return;
    int d = dst[e];
    int pos = atomicAdd(&cur[d], 1);
    srcs[pos] = nbr[e];
    dsts[pos] = d;
}

// ---------------- LDS-free GEMM: C[M,N] = A[M,K] @ Wt[N,K]^T, all bf16 -------
template<int K>
__global__ __launch_bounds__(256) void gemm_nl(const bf16_t* __restrict__ A,
                                               const bf16_t* __restrict__ Wt,
                                               bf16_t* __restrict__ C,
                                               int M, int N) {
    const int w = threadIdx.x >> 6;
    const int lane = threadIdx.x & 63;
    const int lm = lane & 15;
    const int lq = lane >> 4;
    const int n0 = blockIdx.y * 64;
    const int r0 = blockIdx.x * 128 + w * 32;
    int ra0 = r0 + lm;       if (ra0 > M - 1) ra0 = M - 1;
    int ra1 = r0 + 16 + lm;  if (ra1 > M - 1) ra1 = M - 1;
    const bf16_t* A0 = A + (size_t)ra0 * K + lq * 8;
    const bf16_t* A1 = A + (size_t)ra1 * K + lq * 8;
    const bf16_t* B0 = Wt + (size_t)(n0 + lm) * K + lq * 8;
    f32x4 acc[2][4] = {};
#pragma unroll
    for (int kt = 0; kt < K / 32; ++kt) {
        bf16x8 a0 = *(const bf16x8*)(A0 + kt * 32);
        bf16x8 a1 = *(const bf16x8*)(A1 + kt * 32);
#pragma unroll
        for (int nt = 0; nt < 4; ++nt) {
            bf16x8 b = *(const bf16x8*)(B0 + (size_t)nt * 16 * K + kt * 32);
            acc[0][nt] = __builtin_amdgcn_mfma_f32_16x16x32_bf16(a0, b, acc[0][nt], 0, 0, 0);
            acc[1][nt] = __builtin_amdgcn_mfma_f32_16x16x32_bf16(a1, b, acc[1][nt], 0, 0, 0);
        }
    }
#pragma unroll
    for (int rt = 0; rt < 2; ++rt) {
        const int crow0 = r0 + rt * 16 + lq * 4;
#pragma unroll
        for (int nt = 0; nt < 4; ++nt) {
            int col = n0 + nt * 16 + lm;
#pragma unroll
            for (int i = 0; i < 4; ++i) {
                int r = crow0 + i;
                if (r < M) C[(size_t)r * N + col] = (bf16_t)acc[rt][nt][i];
            }
        }
    }
}

// ---------------- a_s = sum_c h[n,h,c]*att[h,c] : one wave per node ----------
__global__ __launch_bounds__(256) void att_dot(const bf16_t* __restrict__ Hb,
                                               const void* __restrict__ att,
                                               float* __restrict__ out,
                                               int Nn, int HD, int H,
                                               const int* __restrict__ flag) {
    int fp32 = flag[0];
    int wid = (blockIdx.x * 256 + threadIdx.x) >> 6;
    int lane = threadIdx.x & 63;
    if (wid >= Nn) return;
    const bf16_t* hp = Hb + (size_t)wid * HD;
    float p0 = (float)hp[lane] * ldin(att, lane, fp32);
    float p1 = 0.f;
    if (HD > 64) p1 = (float)hp[64 + lane] * ldin(att, 64 + lane, fp32);
    for (int off = 32; off; off >>= 1) {
        p0 += __shfl_down(p0, off);
        p1 += __shfl_down(p1, off);
    }
    if (lane == 0) {
        out[(size_t)wid * H] = p0;
        if (H == 2) out[(size_t)wid * H + 1] = p1;
    }
}

// ---------------- edge-parallel exp(leaky(as[src]+ad[dst])) in CSR order -----
// 500k independent threads; gathers hit L2/L3 (tables < 1.6 MB). Removes all
// exp/leaky VALU and as_/ad_ gathers from the wave-serial aggregate loop.
template<int H>
__global__ __launch_bounds__(256) void edge_ex(const int* __restrict__ srcs,
                                               const int* __restrict__ dsts,
                                               const float* __restrict__ as_,
                                               const float* __restrict__ ad_,
                                               float* __restrict__ ex, int E) {
    int i = blockIdx.x * 256 + threadIdx.x;
    if (i >= E) return;
    int s = srcs[i], d = dsts[i];
    if constexpr (H == 2) {
        f32x2 a = *(const f32x2*)(as_ + 2 * (size_t)s);
        f32x2 b = *(const f32x2*)(ad_ + 2 * (size_t)d);
        float v0 = a[0] + b[0]; v0 = v0 > 0.f ? v0 : 0.2f * v0;
        float v1 = a[1] + b[1]; v1 = v1 > 0.f ? v1 : 0.2f * v1;
        f32x2 o;
        o[0] = __expf(fminf(v0, 60.f));
        o[1] = __expf(fminf(v1, 60.f));
        *(f32x2*)(ex + 2 * (size_t)i) = o;
    } else {
        float v = as_[s] + ad_[d];
        v = v > 0.f ? v : 0.2f * v;
        ex[i] = __expf(fminf(v, 60.f));
    }
}

// ---------------- fused segment-softmax + aggregate --------------------------
// Round-0 structure (proven 1 TB/s): one wave per destination, SERIAL edge
// loop, 64 lanes own one full 256B H-row (perfect coalescing), everything
// else wave-uniform scalar loads (srcs[j], ex[j]).
// New vs round 0: (a) ex[] precomputed -> loop body is ~4 VALU + 1 vec load;
// (b) denominator accumulated IN the same loop (ex is wave-uniform, each lane
// tracks its own head's den locally) -> no separate den pass, no reduce;
// (c) MODE 0 fuses ad2 = relu(out).V2 (replaces gemv_att dispatches).
template<int HD, int MODE>
__global__ __launch_bounds__(256) void aggregate(const int* __restrict__ rs,
                                                 const int* __restrict__ srcs,
                                                 const float* __restrict__ ex,
                                                 const bf16_t* __restrict__ Hm,
                                                 const void* __restrict__ bias,
                                                 void* __restrict__ outb, size_t obase,
                                                 const float* __restrict__ V2,
                                                 float* __restrict__ ad2,
                                                 int Nd, const int* __restrict__ flag) {
    constexpr int NH = HD / 64;       // heads: 2 (layer1) or 1 (layer2)
    int wid = (blockIdx.x * 256 + threadIdx.x) >> 6;
    int lane = threadIdx.x & 63;
    if (wid >= Nd) return;
    int start = rs[wid], end = rs[wid + 1];
    int fp32 = flag[0];
    const int hsel = lane >> 5;       // which head this lane's channels use

    float den = 0.f, acc0 = 0.f, acc1 = 0.f;
#pragma unroll 4
    for (int j = start; j < end; ++j) {
        int s = srcs[j];                               // wave-uniform scalar
        if constexpr (NH == 2) {
            f32x2 e = *(const f32x2*)(ex + 2 * (size_t)j);   // wave-uniform
            float eh = hsel ? e[1] : e[0];
            den += eh;
            bf16x2 hv = *(const bf16x2*)(Hm + (size_t)s * 128 + 2 * lane);
            acc0 += (float)hv[0] * eh;
            acc1 += (float)hv[1] * eh;
        } else {
            float eh = ex[j];                          // wave-uniform
            den += eh;
            acc0 += (float)Hm[(size_t)s * 64 + lane] * eh;
        }
    }
    float inv = 1.f / (den + 1e-16f);

    if constexpr (MODE == 0) {
        int c0 = 2 * lane;
        float o0 = fmaxf(acc0 * inv + ldin(bias, c0, fp32), 0.f);
        float o1 = fmaxf(acc1 * inv + ldin(bias, c0 + 1, fp32), 0.f);
        bf16x2 ov;
        ov[0] = (bf16_t)o0;
        ov[1] = (bf16_t)o1;
        *(bf16x2*)((bf16_t*)outb + (size_t)wid * 128 + c0) = ov;
        float pp = o0 * V2[c0] + o1 * V2[c0 + 1];
        for (int off = 32; off; off >>= 1) pp += __shfl_down(pp, off);
        if (lane == 0) ad2[wid] = pp;
    } else {
        float o = acc0 * inv + ldin(bias, lane, fp32);
        size_t oi = obase + (size_t)wid * 64 + lane;
        if (fp32) ((float*)outb)[oi] = o;
        else      ((bf16_t*)outb)[oi] = (bf16_t)o;
    }
}

extern "C" void kernel_launch(void* const* d_in, const int* in_sizes, int n_in,
                              void* d_out, int out_size, void* d_ws, size_t ws_size,
                              hipStream_t stream) {
    const void* xc = d_in[0];
    const void* xp = d_in[1];
    const int* esrc = (const int*)d_in[2];   // customer ids
    const int* edst = (const int*)d_in[3];   // product ids
    const void* w1b_src = d_in[4];
    const void* w1b_dst = d_in[5];
    const void* a1b_src = d_in[6];
    const void* a1b_dst = d_in[7];
    const void* b1b     = d_in[8];
    const void* w1r_src = d_in[9];
    const void* w1r_dst = d_in[10];
    const void* a1r_src = d_in[11];
    const void* a1r_dst = d_in[12];
    const void* b1r     = d_in[13];
    const void* w2b_src = d_in[14];
    const void* w2b_dst = d_in[15];
    const void* a2b_src = d_in[16];
    const void* a2b_dst = d_in[17];
    const void* b2b     = d_in[18];
    const void* w2r_src = d_in[19];
    const void* w2r_dst = d_in[20];
    const void* a2r_src = d_in[21];
    const void* a2r_dst = d_in[22];
    const void* b2r     = d_in[23];

    // -------- workspace layout: NO aliasing (~180 MB, ws proven >= 199 MB) ----
    char* p = (char*)d_ws;
    auto alloc = [&](size_t nbytes) {
        char* r = p;
        p += (nbytes + 255) & ~(size_t)255;
        return r;
    };
    int* flag   = (int*)alloc(256);
    float* V1bd = (float*)alloc(256 * 4);
    float* V1rd = (float*)alloc(512 * 4);
    float* V2bd = (float*)alloc(128 * 4);
    float* V2rd = (float*)alloc(128 * 4);
    bf16_t* Wt1b = (bf16_t*)alloc(128 * 256 * 2);
    bf16_t* Wt1r = (bf16_t*)alloc(128 * 128 * 2);
    bf16_t* Wt2b = (bf16_t*)alloc(64 * 128 * 2);
    bf16_t* Wt2r = (bf16_t*)alloc(64 * 128 * 2);
    float* as_s = (float*)alloc((size_t)NCn * 2 * 4);
    float* ad_b = (float*)alloc((size_t)NPn * 2 * 4);
    float* ad_r = (float*)alloc((size_t)NCn * 2 * 4);
    float* ad2_b = (float*)alloc((size_t)NPn * 4);
    float* ad2_r = (float*)alloc((size_t)NCn * 4);
    int* rsB    = (int*)alloc((size_t)(NPn + 1) * 4);
    int* rsR    = (int*)alloc((size_t)(NCn + 1) * 4);
    int* srcsB  = (int*)alloc((size_t)NE * 4);
    int* srcsR  = (int*)alloc((size_t)NE * 4);
    int* dstsB  = (int*)alloc((size_t)NE * 4);
    int* dstsR  = (int*)alloc((size_t)NE * 4);
    float* exB  = (float*)alloc((size_t)NE * 2 * 4);
    float* exR  = (float*)alloc((size_t)NE * 2 * 4);
    int* cntB   = (int*)alloc((size_t)NPn * 4);
    int* cntR   = (int*)alloc((size_t)NCn * 4);
    int* bsum   = (int*)alloc(128 * 4);
    bf16_t* xcb = (bf16_t*)alloc((size_t)NCn * 256 * 2);
    bf16_t* xpb = (bf16_t*)alloc((size_t)NPn * 128 * 2);
    bf16_t* Hc  = (bf16_t*)alloc((size_t)NCn * 128 * 2);
    bf16_t* Hp  = (bf16_t*)alloc((size_t)NPn * 128 * 2);
    bf16_t* c1  = (bf16_t*)alloc((size_t)NCn * 128 * 2);
    bf16_t* p1  = (bf16_t*)alloc((size_t)NPn * 128 * 2);
    bf16_t* Hc2 = (bf16_t*)alloc((size_t)NCn * 64 * 2);
    bf16_t* Hp2 = (bf16_t*)alloc((size_t)NPn * 64 * 2);

    const dim3 blk(256);
    const int gE = (NE + 255) / 256;
    const int sbP = (NPn + 1023) / 1024;
    const int sbR = (NCn + 1023) / 1024;
    const int gmC = (NCn + 127) / 128;
    const int gmP = (NPn + 127) / 128;
    const int gNP = (NPn + 255) / 256;
    const int gNC = (NCn + 255) / 256;

    detect_dtype<<<1, 64, 0, stream>>>(xc, flag);
    prep_V<<<1, 256, 0, stream>>>(flag, w1b_dst, a1b_dst, w1r_dst, a1r_dst,
                                  w2b_dst, a2b_dst, w2r_dst, a2r_dst,
                                  V1bd, V1rd, V2bd, V2rd);
    prep_w<<<128, blk, 0, stream>>>(w1b_src, Wt1b, 128, 8, flag);
    prep_w<<<64,  blk, 0, stream>>>(w1r_src, Wt1r, 128, 7, flag);
    prep_w<<<32,  blk, 0, stream>>>(w2b_src, Wt2b, 64, 7, flag);
    prep_w<<<32,  blk, 0, stream>>>(w2r_src, Wt2r, 64, 7, flag);

    // -------- CSR build dir b (dst = product) --------
    zero_int<<<gNP, blk, 0, stream>>>(cntB, NPn);
    hist_k<<<gE, blk, 0, stream>>>(edst, cntB, NE);
    scan_blocks<<<sbP, blk, 0, stream>>>(cntB, rsB, bsum, NPn);
    scan_bsum<<<1, 128, 0, stream>>>(bsum, sbP);
    scan_add<<<gNP + 1, blk, 0, stream>>>(rsB, bsum, NPn, NE);
    copy_int<<<gNP, blk, 0, stream>>>(rsB, cntB, NPn);
    scatter_k<<<gE, blk, 0, stream>>>(edst, esrc, cntB, srcsB, dstsB, NE);

    // -------- CSR build dir r (dst = customer) --------
    zero_int<<<gNC, blk, 0, stream>>>(cntR, NCn);
    hist_k<<<gE, blk, 0, stream>>>(esrc, cntR, NE);
    scan_blocks<<<sbR, blk, 0, stream>>>(cntR, rsR, bsum, NCn);
    scan_bsum<<<1, 128, 0, stream>>>(bsum, sbR);
    scan_add<<<gNC + 1, blk, 0, stream>>>(rsR, bsum, NCn, NE);
    copy_int<<<gNC, blk, 0, stream>>>(rsR, cntR, NCn);
    scatter_k<<<gE, blk, 0, stream>>>(esrc, edst, cntR, srcsR, dstsR, NE);

    // -------- convert inputs to bf16 + fused L1 dst scores --------
    cvt_rows<256><<<(NCn + 3) / 4, blk, 0, stream>>>(xc, xcb, V1rd, ad_r, NCn, flag);
    cvt_rows<128><<<(NPn + 3) / 4, blk, 0, stream>>>(xp, xpb, V1bd, ad_b, NPn, flag);

    // -------- layer 1 src projections --------
    gemm_nl<256><<<dim3(gmC, 2), blk, 0, stream>>>(xcb, Wt1b, Hc, NCn, 128);
    gemm_nl<128><<<dim3(gmP, 2), blk, 0, stream>>>(xpb, Wt1r, Hp, NPn, 128);

    // ---- L1 dir b (customer -> product) -> p1 (+ fused ad2_b = p1.V2bd) ----
    att_dot<<<(NCn + 3) / 4, blk, 0, stream>>>(Hc, a1b_src, as_s, NCn, 128, 2, flag);
    edge_ex<2><<<gE, blk, 0, stream>>>(srcsB, dstsB, as_s, ad_b, exB, NE);
    aggregate<128, 0><<<(NPn + 3) / 4, blk, 0, stream>>>(rsB, srcsB, exB, Hc, b1b, p1, 0, V2bd, ad2_b, NPn, flag);

    // ---- L1 dir r (product -> customer) -> c1 (+ fused ad2_r = c1.V2rd) ----
    att_dot<<<(NPn + 3) / 4, blk, 0, stream>>>(Hp, a1r_src, as_s, NPn, 128, 2, flag);
    edge_ex<2><<<gE, blk, 0, stream>>>(srcsR, dstsR, as_s, ad_r, exR, NE);
    aggregate<128, 0><<<(NCn + 3) / 4, blk, 0, stream>>>(rsR, srcsR, exR, Hp, b1r, c1, 0, V2rd, ad2_r, NCn, flag);

    // -------- layer 2 src projections --------
    gemm_nl<128><<<dim3(gmC, 1), blk, 0, stream>>>(c1, Wt2b, Hc2, NCn, 64);
    gemm_nl<128><<<dim3(gmP, 1), blk, 0, stream>>>(p1, Wt2r, Hp2, NPn, 64);

    // ---- L2 dir b -> p2 (second half of d_out) ----
    att_dot<<<(NCn + 3) / 4, blk, 0, stream>>>(Hc2, a2b_src, as_s, NCn, 64, 1, flag);
    edge_ex<1><<<gE, blk, 0, stream>>>(srcsB, dstsB, as_s, ad2_b, exB, NE);
    aggregate<64, 1><<<(NPn + 3) / 4, blk, 0, stream>>>(rsB, srcsB, exB, Hc2, b2b, d_out, (size_t)NCn * 64, nullptr, nullptr, NPn, flag);

    // ---- L2 dir r -> c2 (first half of d_out) ----
    att_dot<<<(NPn + 3) / 4, blk, 0, stream>>>(Hp2, a2r_src, as_s, NPn, 64, 1, flag);
    edge_ex<1><<<gE, blk, 0, stream>>>(srcsR, dstsR, as_s, ad2_r, exR, NE);
    aggregate<64, 1><<<(NCn + 3) / 4, blk, 0, stream>>>(rsR, srcsR, exR, Hp2, b2r, d_out, 0, nullptr, nullptr, NCn, flag);
}

// Round 4
// 622.865 us; speedup vs baseline: 1.4957x; 1.1516x over previous
//
#include <hip/hip_runtime.h>
#include <hip/hip_bf16.h>

typedef __bf16 bf16_t;
typedef bf16_t bf16x2 __attribute__((ext_vector_type(2)));
typedef bf16_t bf16x4 __attribute__((ext_vector_type(4)));
typedef bf16_t bf16x8 __attribute__((ext_vector_type(8)));
typedef float f32x2 __attribute__((ext_vector_type(2)));
typedef float f32x4 __attribute__((ext_vector_type(4)));

static constexpr int NCn = 100000;
static constexpr int NPn = 50000;
static constexpr int NE  = 500000;

// Dual-dtype input load: inputs may be fp32 or bf16 (runtime-detected flag).
__device__ __forceinline__ float ldin(const void* p, size_t i, int fp32) {
    return fp32 ? ((const float*)p)[i] : (float)((const bf16_t*)p)[i];
}

// ---- dtype detect + fold dst-projections against attention vectors ---------
// V[k,h] = sum_c W[k,h*C+c]*att[h,c]
__global__ __launch_bounds__(256) void prep_meta(const void* x, int* flag,
                                                 const void* w1bd, const void* a1bd,
                                                 const void* w1rd, const void* a1rd,
                                                 const void* w2bd, const void* a2bd,
                                                 const void* w2rd, const void* a2rd,
                                                 float* V1bd, float* V1rd,
                                                 float* V2bd, float* V2rd) {
    __shared__ int sflag;
    int t = threadIdx.x;
    if (t < 64) {
        const bf16_t* xb = (const bf16_t*)x;
        int bad = 0;
        for (int i = t; i < 512; i += 64) {
            float v = (float)xb[i];
            if (!(v > -1e4f && v < 1e4f)) bad = 1;
        }
        unsigned long long m = __ballot(bad);
        if (t == 0) { sflag = (m != 0ull) ? 1 : 0; flag[0] = sflag; }
    }
    __syncthreads();
    int fp32 = sflag;
    for (int idx = t; idx < 256; idx += 256) {          // V1bd: k<128, h<2
        int k = idx >> 1, h = idx & 1;
        float s = 0.f;
        for (int c = 0; c < 64; ++c)
            s += ldin(w1bd, (size_t)k * 128 + h * 64 + c, fp32) * ldin(a1bd, h * 64 + c, fp32);
        V1bd[k * 2 + h] = s;
    }
    for (int idx = t; idx < 512; idx += 256) {          // V1rd: k<256, h<2
        int k = idx >> 1, h = idx & 1;
        float s = 0.f;
        for (int c = 0; c < 64; ++c)
            s += ldin(w1rd, (size_t)k * 128 + h * 64 + c, fp32) * ldin(a1rd, h * 64 + c, fp32);
        V1rd[k * 2 + h] = s;
    }
    for (int k = t; k < 128; k += 256) {                // V2bd
        float s = 0.f;
        for (int c = 0; c < 64; ++c)
            s += ldin(w2bd, (size_t)k * 64 + c, fp32) * ldin(a2bd, c, fp32);
        V2bd[k] = s;
    }
    for (int k = t; k < 128; k += 256) {                // V2rd
        float s = 0.f;
        for (int c = 0; c < 64; ++c)
            s += ldin(w2rd, (size_t)k * 64 + c, fp32) * ldin(a2rd, c, fp32);
        V2rd[k] = s;
    }
}

// All 4 weight transposes (W[K][N] -> Wt[N][K] bf16) in one dispatch (256 blocks).
__global__ __launch_bounds__(256) void prep_w4(const void* __restrict__ w1b, bf16_t* __restrict__ Wt1b,
                                               const void* __restrict__ w1r, bf16_t* __restrict__ Wt1r,
                                               const void* __restrict__ w2b, bf16_t* __restrict__ Wt2b,
                                               const void* __restrict__ w2r, bf16_t* __restrict__ Wt2r,
                                               const int* __restrict__ flag) {
    int fp32 = flag[0];
    int b = blockIdx.x;
    const void* W; bf16_t* Wt; int N, ks, base;
    if (b < 128)      { W = w1b; Wt = Wt1b; N = 128; ks = 8; base = 0;   }
    else if (b < 192) { W = w1r; Wt = Wt1r; N = 128; ks = 7; base = 128; }
    else if (b < 224) { W = w2b; Wt = Wt2b; N = 64;  ks = 7; base = 192; }
    else              { W = w2r; Wt = Wt2r; N = 64;  ks = 7; base = 224; }
    int idx = (b - base) * 256 + threadIdx.x;
    int K = 1 << ks;
    int n = idx >> ks, k = idx & (K - 1);
    if (n < N) Wt[idx] = (bf16_t)ldin(W, (size_t)k * N + n, fp32);
}

// Convert X[M][K] (flag dtype) -> bf16, fused with ad[m,h] = X[m,:] @ V[:,h].
template<int K>
__global__ __launch_bounds__(256) void cvt_rows(const void* __restrict__ X,
                                                bf16_t* __restrict__ Xb,
                                                const float* __restrict__ V,
                                                float* __restrict__ ad,
                                                int M, const int* __restrict__ flag) {
    constexpr int EPL = K / 64;
    int fp32 = flag[0];
    int wid = (blockIdx.x * 256 + threadIdx.x) >> 6;
    int lane = threadIdx.x & 63;
    if (wid >= M) return;
    size_t base = (size_t)wid * K + lane * EPL;
    float x[EPL];
    if constexpr (EPL == 4) {
        if (fp32) { f32x4 t = *(const f32x4*)((const float*)X + base);
#pragma unroll
            for (int j = 0; j < 4; ++j) x[j] = t[j];
        } else { bf16x4 t = *(const bf16x4*)((const bf16_t*)X + base);
#pragma unroll
            for (int j = 0; j < 4; ++j) x[j] = (float)t[j];
        }
        bf16x4 o;
#pragma unroll
        for (int j = 0; j < 4; ++j) o[j] = (bf16_t)x[j];
        *(bf16x4*)(Xb + base) = o;
    } else {
        if (fp32) { f32x2 t = *(const f32x2*)((const float*)X + base);
#pragma unroll
            for (int j = 0; j < 2; ++j) x[j] = t[j];
        } else { bf16x2 t = *(const bf16x2*)((const bf16_t*)X + base);
#pragma unroll
            for (int j = 0; j < 2; ++j) x[j] = (float)t[j];
        }
        bf16x2 o;
#pragma unroll
        for (int j = 0; j < 2; ++j) o[j] = (bf16_t)x[j];
        *(bf16x2*)(Xb + base) = o;
    }
    float a0 = 0.f, a1 = 0.f;
#pragma unroll
    for (int j = 0; j < EPL; ++j) {
        int k = lane * EPL + j;
        a0 += x[j] * V[k * 2];
        a1 += x[j] * V[k * 2 + 1];
    }
    for (int off = 32; off; off >>= 1) {
        a0 += __shfl_down(a0, off);
        a1 += __shfl_down(a1, off);
    }
    if (lane == 0) { ad[(size_t)wid * 2] = a0; ad[(size_t)wid * 2 + 1] = a1; }
}

// ---------------- CSR build (both directions fused) --------------------------
__global__ __launch_bounds__(256) void zero2(int* __restrict__ a, int na,
                                             int* __restrict__ b, int nb) {
    int i = blockIdx.x * 256 + threadIdx.x;
    if (i < na) a[i] = 0;
    else if (i - na < nb) b[i - na] = 0;
}

__global__ __launch_bounds__(256) void hist2(const int* __restrict__ esrc,
                                             const int* __restrict__ edst,
                                             int* __restrict__ cntR,
                                             int* __restrict__ cntB, int E) {
    int e = blockIdx.x * 256 + threadIdx.x;
    if (e >= E) return;
    atomicAdd(&cntB[edst[e]], 1);
    atomicAdd(&cntR[esrc[e]], 1);
}

__global__ __launch_bounds__(256) void scan_blocks(const int* __restrict__ cnt,
                                                   int* __restrict__ rs,
                                                   int* __restrict__ bsum, int N) {
    int t = threadIdx.x, b = blockIdx.x;
    int base = b * 1024 + t * 4;
    int c[4];
#pragma unroll
    for (int k = 0; k < 4; ++k) { int i = base + k; c[k] = (i < N) ? cnt[i] : 0; }
    int tsum = c[0] + c[1] + c[2] + c[3];
    __shared__ int sd[256];
    sd[t] = tsum;
    __syncthreads();
    for (int off = 1; off < 256; off <<= 1) {
        int x = (t >= off) ? sd[t - off] : 0;
        __syncthreads();
        sd[t] += x;
        __syncthreads();
    }
    int run = sd[t] - tsum;
#pragma unroll
    for (int k = 0; k < 4; ++k) { int i = base + k; if (i < N) rs[i] = run; run += c[k]; }
    if (t == 255) bsum[b] = sd[255];
}

__global__ __launch_bounds__(128) void scan_bsum2(int* __restrict__ bsumB, int nbB,
                                                  int* __restrict__ bsumR, int nbR) {
    int* bsum = blockIdx.x ? bsumR : bsumB;
    int nb = blockIdx.x ? nbR : nbB;
    int t = threadIdx.x;
    __shared__ int sd[128];
    int v = (t < nb) ? bsum[t] : 0;
    sd[t] = v;
    __syncthreads();
    for (int off = 1; off < 128; off <<= 1) {
        int x = (t >= off) ? sd[t - off] : 0;
        __syncthreads();
        sd[t] += x;
        __syncthreads();
    }
    if (t < nb) bsum[t] = sd[t] - v;
}

// rs += carry; also seed the scatter cursors (cnt = rs) and the sentinels.
__global__ __launch_bounds__(256) void scan_add2(int* __restrict__ rsB, const int* __restrict__ bsumB,
                                                 int NB, int* __restrict__ cntB,
                                                 int* __restrict__ rsR, const int* __restrict__ bsumR,
                                                 int NR, int* __restrict__ cntR, int E) {
    int i = blockIdx.x * 256 + threadIdx.x;
    if (i < NB) { int v = rsB[i] + bsumB[i >> 10]; rsB[i] = v; cntB[i] = v; }
    if (i < NR) { int v = rsR[i] + bsumR[i >> 10]; rsR[i] = v; cntR[i] = v; }
    if (i == 0) { rsB[NB] = E; rsR[NR] = E; }
}

__global__ __launch_bounds__(256) void scatter2(const int* __restrict__ esrc,
                                                const int* __restrict__ edst,
                                                int* __restrict__ curB, int* __restrict__ curR,
                                                int* __restrict__ srcsB, int* __restrict__ dstsB,
                                                int* __restrict__ srcsR, int* __restrict__ dstsR,
                                                int E) {
    int e = blockIdx.x * 256 + threadIdx.x;
    if (e >= E) return;
    int s = esrc[e], d = edst[e];
    int pb = atomicAdd(&curB[d], 1);
    srcsB[pb] = s; dstsB[pb] = d;
    int pr = atomicAdd(&curR[s], 1);
    srcsR[pr] = d; dstsR[pr] = s;
}

// ---------------- LDS-free GEMM: C[M,N] = A[M,K] @ Wt[N,K]^T, all bf16 -------
// Fused att epilogue: blockIdx.y covers exactly one head's 64 columns, so each
// block computes the COMPLETE head dot as[r,h] = sum_c H[r,h*64+c]*att[h,c]
// from the fp32 accumulators (32 FMA + 4 shfl_xor rounds; no atomics).
template<int K>
__global__ __launch_bounds__(256) void gemm_nl(const bf16_t* __restrict__ A,
                                               const bf16_t* __restrict__ Wt,
                                               bf16_t* __restrict__ C,
                                               const void* __restrict__ att,
                                               float* __restrict__ asout, int H,
                                               int M, int N,
                                               const int* __restrict__ flag) {
    const int w = threadIdx.x >> 6;
    const int lane = threadIdx.x & 63;
    const int lm = lane & 15;
    const int lq = lane >> 4;
    const int n0 = blockIdx.y * 64;
    const int r0 = blockIdx.x * 128 + w * 32;
    int ra0 = r0 + lm;       if (ra0 > M - 1) ra0 = M - 1;
    int ra1 = r0 + 16 + lm;  if (ra1 > M - 1) ra1 = M - 1;
    const bf16_t* A0 = A + (size_t)ra0 * K + lq * 8;
    const bf16_t* A1 = A + (size_t)ra1 * K + lq * 8;
    const bf16_t* B0 = Wt + (size_t)(n0 + lm) * K + lq * 8;
    f32x4 acc[2][4] = {};
#pragma unroll
    for (int kt = 0; kt < K / 32; ++kt) {
        bf16x8 a0 = *(const bf16x8*)(A0 + kt * 32);
        bf16x8 a1 = *(const bf16x8*)(A1 + kt * 32);
#pragma unroll
        for (int nt = 0; nt < 4; ++nt) {
            bf16x8 b = *(const bf16x8*)(B0 + (size_t)nt * 16 * K + kt * 32);
            acc[0][nt] = __builtin_amdgcn_mfma_f32_16x16x32_bf16(a0, b, acc[0][nt], 0, 0, 0);
            acc[1][nt] = __builtin_amdgcn_mfma_f32_16x16x32_bf16(a1, b, acc[1][nt], 0, 0, 0);
        }
    }
#pragma unroll
    for (int rt = 0; rt < 2; ++rt) {
        const int crow0 = r0 + rt * 16 + lq * 4;
#pragma unroll
        for (int nt = 0; nt < 4; ++nt) {
            int col = n0 + nt * 16 + lm;
#pragma unroll
            for (int i = 0; i < 4; ++i) {
                int r = crow0 + i;
                if (r < M) C[(size_t)r * N + col] = (bf16_t)acc[rt][nt][i];
            }
        }
    }
    // ---- fused attention-dot epilogue ----
    int fp32 = flag[0];
    float attv[4];
#pragma unroll
    for (int nt = 0; nt < 4; ++nt) attv[nt] = ldin(att, n0 + nt * 16 + lm, fp32);
    float part[2][4];
#pragma unroll
    for (int rt = 0; rt < 2; ++rt)
#pragma unroll
        for (int i = 0; i < 4; ++i) {
            float s = 0.f;
#pragma unroll
            for (int nt = 0; nt < 4; ++nt) s += acc[rt][nt][i] * attv[nt];
            part[rt][i] = s;
        }
#pragma unroll
    for (int off = 1; off < 16; off <<= 1)
#pragma unroll
        for (int rt = 0; rt < 2; ++rt)
#pragma unroll
            for (int i = 0; i < 4; ++i)
                part[rt][i] += __shfl_xor(part[rt][i], off);
    if (lm == 0) {
#pragma unroll
        for (int rt = 0; rt < 2; ++rt)
#pragma unroll
            for (int i = 0; i < 4; ++i) {
                int r = r0 + rt * 16 + lq * 4 + i;
                if (r < M) asout[(size_t)r * H + blockIdx.y] = part[rt][i];
            }
    }
}

// ---------------- edge-parallel exp(leaky(as[src]+ad[dst])), both dirs -------
template<int H>
__global__ __launch_bounds__(256) void edge_ex2(const int* __restrict__ srcsB,
                                                const int* __restrict__ dstsB,
                                                const float* __restrict__ asB,
                                                const float* __restrict__ adB,
                                                float* __restrict__ exBp,
                                                const int* __restrict__ srcsR,
                                                const int* __restrict__ dstsR,
                                                const float* __restrict__ asR,
                                                const float* __restrict__ adR,
                                                float* __restrict__ exRp, int E) {
    int i = blockIdx.x * 256 + threadIdx.x;
    const int *srcs, *dsts; const float *as_, *ad_; float* ex; int j;
    if (i < E) { j = i; srcs = srcsB; dsts = dstsB; as_ = asB; ad_ = adB; ex = exBp; }
    else {
        j = i - E;
        if (j >= E) return;
        srcs = srcsR; dsts = dstsR; as_ = asR; ad_ = adR; ex = exRp;
    }
    int s = srcs[j], d = dsts[j];
    if constexpr (H == 2) {
        f32x2 a = *(const f32x2*)(as_ + 2 * (size_t)s);
        f32x2 b = *(const f32x2*)(ad_ + 2 * (size_t)d);
        float v0 = a[0] + b[0]; v0 = v0 > 0.f ? v0 : 0.2f * v0;
        float v1 = a[1] + b[1]; v1 = v1 > 0.f ? v1 : 0.2f * v1;
        f32x2 o;
        o[0] = __expf(fminf(v0, 60.f));
        o[1] = __expf(fminf(v1, 60.f));
        *(f32x2*)(ex + 2 * (size_t)j) = o;
    } else {
        float v = as_[s] + ad_[d];
        v = v > 0.f ? v : 0.2f * v;
        ex[j] = __expf(fminf(v, 60.f));
    }
}

// ---------------- fused segment-softmax + aggregate, both dirs ---------------
// One wave per destination, SERIAL edge loop (proven 1 TB/s structure):
// 64 lanes own one full H-row (perfect coalescing), srcs[j]/ex[j] are
// wave-uniform scalar loads, denominator accumulated in the same loop.
// MODE 0 (layer1, HD=128): relu + bf16 out + fused ad2 = relu(out) . V2.
// MODE 1 (layer2, HD=64): final output, dtype per flag, no relu.
template<int HD, int MODE>
__global__ __launch_bounds__(256) void aggregate2(
        const int* __restrict__ rsB, const int* __restrict__ srcsB,
        const float* __restrict__ exB, const bf16_t* __restrict__ HmB,
        const void* __restrict__ biasB, const float* __restrict__ V2B,
        float* __restrict__ ad2B, void* __restrict__ outB, size_t obaseB, int NdB,
        const int* __restrict__ rsR, const int* __restrict__ srcsR,
        const float* __restrict__ exR, const bf16_t* __restrict__ HmR,
        const void* __restrict__ biasR, const float* __restrict__ V2R,
        float* __restrict__ ad2R, void* __restrict__ outR, size_t obaseR, int NdR,
        const int* __restrict__ flag) {
    constexpr int NH = HD / 64;       // heads: 2 (layer1) or 1 (layer2)
    int gw = (blockIdx.x * 256 + threadIdx.x) >> 6;
    int lane = threadIdx.x & 63;
    const int* rs; const int* srcs; const float* ex; const bf16_t* Hm;
    const void* bias; const float* V2; float* ad2; void* outb; size_t obase; int wid;
    if (gw < NdB) {
        wid = gw;
        rs = rsB; srcs = srcsB; ex = exB; Hm = HmB; bias = biasB;
        V2 = V2B; ad2 = ad2B; outb = outB; obase = obaseB;
    } else {
        wid = gw - NdB;
        if (wid >= NdR) return;
        rs = rsR; srcs = srcsR; ex = exR; Hm = HmR; bias = biasR;
        V2 = V2R; ad2 = ad2R; outb = outR; obase = obaseR;
    }
    int start = rs[wid], end = rs[wid + 1];
    int fp32 = flag[0];
    const int hsel = lane >> 5;       // which head this lane's channels use

    float den = 0.f, acc0 = 0.f, acc1 = 0.f;
#pragma unroll 4
    for (int j = start; j < end; ++j) {
        int s = srcs[j];                               // wave-uniform scalar
        if constexpr (NH == 2) {
            f32x2 e = *(const f32x2*)(ex + 2 * (size_t)j);   // wave-uniform
            float eh = hsel ? e[1] : e[0];
            den += eh;
            bf16x2 hv = *(const bf16x2*)(Hm + (size_t)s * 128 + 2 * lane);
            acc0 += (float)hv[0] * eh;
            acc1 += (float)hv[1] * eh;
        } else {
            float eh = ex[j];                          // wave-uniform
            den += eh;
            acc0 += (float)Hm[(size_t)s * 64 + lane] * eh;
        }
    }
    float inv = 1.f / (den + 1e-16f);

    if constexpr (MODE == 0) {
        int c0 = 2 * lane;
        float o0 = fmaxf(acc0 * inv + ldin(bias, c0, fp32), 0.f);
        float o1 = fmaxf(acc1 * inv + ldin(bias, c0 + 1, fp32), 0.f);
        bf16x2 ov;
        ov[0] = (bf16_t)o0;
        ov[1] = (bf16_t)o1;
        *(bf16x2*)((bf16_t*)outb + (size_t)wid * 128 + c0) = ov;
        float pp = o0 * V2[c0] + o1 * V2[c0 + 1];
        for (int off = 32; off; off >>= 1) pp += __shfl_down(pp, off);
        if (lane == 0) ad2[wid] = pp;
    } else {
        float o = acc0 * inv + ldin(bias, lane, fp32);
        size_t oi = obase + (size_t)wid * 64 + lane;
        if (fp32) ((float*)outb)[oi] = o;
        else      ((bf16_t*)outb)[oi] = (bf16_t)o;
    }
}

extern "C" void kernel_launch(void* const* d_in, const int* in_sizes, int n_in,
                              void* d_out, int out_size, void* d_ws, size_t ws_size,
                              hipStream_t stream) {
    const void* xc = d_in[0];
    const void* xp = d_in[1];
    const int* esrc = (const int*)d_in[2];   // customer ids
    const int* edst = (const int*)d_in[3];   // product ids
    const void* w1b_src = d_in[4];
    const void* w1b_dst = d_in[5];
    const void* a1b_src = d_in[6];
    const void* a1b_dst = d_in[7];
    const void* b1b     = d_in[8];
    const void* w1r_src = d_in[9];
    const void* w1r_dst = d_in[10];
    const void* a1r_src = d_in[11];
    const void* a1r_dst = d_in[12];
    const void* b1r     = d_in[13];
    const void* w2b_src = d_in[14];
    const void* w2b_dst = d_in[15];
    const void* a2b_src = d_in[16];
    const void* a2b_dst = d_in[17];
    const void* b2b     = d_in[18];
    const void* w2r_src = d_in[19];
    const void* w2r_dst = d_in[20];
    const void* a2r_src = d_in[21];
    const void* a2r_dst = d_in[22];
    const void* b2r     = d_in[23];

    // -------- workspace layout: NO aliasing (~182 MB, ws proven >= 199 MB) ----
    char* p = (char*)d_ws;
    auto alloc = [&](size_t nbytes) {
        char* r = p;
        p += (nbytes + 255) & ~(size_t)255;
        return r;
    };
    int* flag   = (int*)alloc(256);
    float* V1bd = (float*)alloc(256 * 4);
    float* V1rd = (float*)alloc(512 * 4);
    float* V2bd = (float*)alloc(128 * 4);
    float* V2rd = (float*)alloc(128 * 4);
    bf16_t* Wt1b = (bf16_t*)alloc(128 * 256 * 2);
    bf16_t* Wt1r = (bf16_t*)alloc(128 * 128 * 2);
    bf16_t* Wt2b = (bf16_t*)alloc(64 * 128 * 2);
    bf16_t* Wt2r = (bf16_t*)alloc(64 * 128 * 2);
    float* as_b = (float*)alloc((size_t)NCn * 2 * 4);   // L1-b src scores (customers)
    float* as_r = (float*)alloc((size_t)NPn * 2 * 4);   // L1-r src scores (products)
    float* as2_c = (float*)alloc((size_t)NCn * 4);      // L2-b src scores (customers)
    float* as2_p = (float*)alloc((size_t)NPn * 4);      // L2-r src scores (products)
    float* ad_b = (float*)alloc((size_t)NPn * 2 * 4);
    float* ad_r = (float*)alloc((size_t)NCn * 2 * 4);
    float* ad2_b = (float*)alloc((size_t)NPn * 4);
    float* ad2_r = (float*)alloc((size_t)NCn * 4);
    int* rsB    = (int*)alloc((size_t)(NPn + 1) * 4);
    int* rsR    = (int*)alloc((size_t)(NCn + 1) * 4);
    int* srcsB  = (int*)alloc((size_t)NE * 4);
    int* srcsR  = (int*)alloc((size_t)NE * 4);
    int* dstsB  = (int*)alloc((size_t)NE * 4);
    int* dstsR  = (int*)alloc((size_t)NE * 4);
    float* exB  = (float*)alloc((size_t)NE * 2 * 4);
    float* exR  = (float*)alloc((size_t)NE * 2 * 4);
    int* cntB   = (int*)alloc((size_t)NPn * 4);
    int* cntR   = (int*)alloc((size_t)NCn * 4);
    int* bsumB  = (int*)alloc(128 * 4);
    int* bsumR  = (int*)alloc(128 * 4);
    bf16_t* xcb = (bf16_t*)alloc((size_t)NCn * 256 * 2);
    bf16_t* xpb = (bf16_t*)alloc((size_t)NPn * 128 * 2);
    bf16_t* Hc  = (bf16_t*)alloc((size_t)NCn * 128 * 2);
    bf16_t* Hp  = (bf16_t*)alloc((size_t)NPn * 128 * 2);
    bf16_t* c1  = (bf16_t*)alloc((size_t)NCn * 128 * 2);
    bf16_t* p1  = (bf16_t*)alloc((size_t)NPn * 128 * 2);
    bf16_t* Hc2 = (bf16_t*)alloc((size_t)NCn * 64 * 2);
    bf16_t* Hp2 = (bf16_t*)alloc((size_t)NPn * 64 * 2);

    const dim3 blk(256);
    const int gE = (NE + 255) / 256;
    const int g2E = (2 * NE + 255) / 256;
    const int sbP = (NPn + 1023) / 1024;
    const int sbR = (NCn + 1023) / 1024;
    const int gmC = (NCn + 127) / 128;
    const int gmP = (NPn + 127) / 128;
    const int gNC = (NCn + 255) / 256;
    const int gBoth = (NPn + NCn + 255) / 256;
    const int gAgg = (NPn + NCn + 3) / 4;      // 1 wave per destination, both dirs

    prep_meta<<<1, 256, 0, stream>>>(xc, flag, w1b_dst, a1b_dst, w1r_dst, a1r_dst,
                                     w2b_dst, a2b_dst, w2r_dst, a2r_dst,
                                     V1bd, V1rd, V2bd, V2rd);
    prep_w4<<<256, blk, 0, stream>>>(w1b_src, Wt1b, w1r_src, Wt1r,
                                     w2b_src, Wt2b, w2r_src, Wt2r, flag);

    // -------- CSR build, both directions fused --------
    zero2<<<gBoth, blk, 0, stream>>>(cntB, NPn, cntR, NCn);
    hist2<<<gE, blk, 0, stream>>>(esrc, edst, cntR, cntB, NE);
    scan_blocks<<<sbP, blk, 0, stream>>>(cntB, rsB, bsumB, NPn);
    scan_blocks<<<sbR, blk, 0, stream>>>(cntR, rsR, bsumR, NCn);
    scan_bsum2<<<2, 128, 0, stream>>>(bsumB, sbP, bsumR, sbR);
    scan_add2<<<gNC, blk, 0, stream>>>(rsB, bsumB, NPn, cntB, rsR, bsumR, NCn, cntR, NE);
    scatter2<<<gE, blk, 0, stream>>>(esrc, edst, cntB, cntR, srcsB, dstsB, srcsR, dstsR, NE);

    // -------- convert inputs to bf16 + fused L1 dst scores --------
    cvt_rows<256><<<(NCn + 3) / 4, blk, 0, stream>>>(xc, xcb, V1rd, ad_r, NCn, flag);
    cvt_rows<128><<<(NPn + 3) / 4, blk, 0, stream>>>(xp, xpb, V1bd, ad_b, NPn, flag);

    // -------- layer 1 src projections (+ fused as = H . att_src) --------
    gemm_nl<256><<<dim3(gmC, 2), blk, 0, stream>>>(xcb, Wt1b, Hc, a1b_src, as_b, 2, NCn, 128, flag);
    gemm_nl<128><<<dim3(gmP, 2), blk, 0, stream>>>(xpb, Wt1r, Hp, a1r_src, as_r, 2, NPn, 128, flag);

    // -------- L1 edge scores + aggregates, both dirs each in one dispatch ----
    edge_ex2<2><<<g2E, blk, 0, stream>>>(srcsB, dstsB, as_b, ad_b, exB,
                                         srcsR, dstsR, as_r, ad_r, exR, NE);
    aggregate2<128, 0><<<gAgg, blk, 0, stream>>>(
        rsB, srcsB, exB, Hc, b1b, V2bd, ad2_b, p1, 0, NPn,
        rsR, srcsR, exR, Hp, b1r, V2rd, ad2_r, c1, 0, NCn, flag);

    // -------- layer 2 src projections (+ fused as2 = H2 . att_src) --------
    gemm_nl<128><<<dim3(gmC, 1), blk, 0, stream>>>(c1, Wt2b, Hc2, a2b_src, as2_c, 1, NCn, 64, flag);
    gemm_nl<128><<<dim3(gmP, 1), blk, 0, stream>>>(p1, Wt2r, Hp2, a2r_src, as2_p, 1, NPn, 64, flag);

    // -------- L2 edge scores + final aggregates --------
    edge_ex2<1><<<g2E, blk, 0, stream>>>(srcsB, dstsB, as2_c, ad2_b, exB,
                                         srcsR, dstsR, as2_p, ad2_r, exR, NE);
    aggregate2<64, 1><<<gAgg, blk, 0, stream>>>(
        rsB, srcsB, exB, Hc2, b2b, nullptr, nullptr, d_out, (size_t)NCn * 64, NPn,
        rsR, srcsR, exR, Hp2, b2r, nullptr, nullptr, d_out, 0, NCn, flag);
}

// Round 6
// 598.062 us; speedup vs baseline: 1.5577x; 1.0415x over previous
//
#include <hip/hip_runtime.h>
#include <hip/hip_bf16.h>

typedef __bf16 bf16_t;
typedef bf16_t bf16x2 __attribute__((ext_vector_type(2)));
typedef bf16_t bf16x4 __attribute__((ext_vector_type(4)));
typedef bf16_t bf16x8 __attribute__((ext_vector_type(8)));
typedef float f32x2 __attribute__((ext_vector_type(2)));
typedef float f32x4 __attribute__((ext_vector_type(4)));

static constexpr int NCn = 100000;
static constexpr int NPn = 50000;
static constexpr int NE  = 500000;

// Dual-dtype input load: inputs may be fp32 or bf16 (runtime-detected flag).
__device__ __forceinline__ float ldin(const void* p, size_t i, int fp32) {
    return fp32 ? ((const float*)p)[i] : (float)((const bf16_t*)p)[i];
}

// ---- dtype detect + fold dst-projections against attention vectors ---------
// V[k,h] = sum_c W[k,h*C+c]*att[h,c]
__global__ __launch_bounds__(256) void prep_meta(const void* x, int* flag,
                                                 const void* w1bd, const void* a1bd,
                                                 const void* w1rd, const void* a1rd,
                                                 const void* w2bd, const void* a2bd,
                                                 const void* w2rd, const void* a2rd,
                                                 float* V1bd, float* V1rd,
                                                 float* V2bd, float* V2rd) {
    __shared__ int sflag;
    int t = threadIdx.x;
    if (t < 64) {
        const bf16_t* xb = (const bf16_t*)x;
        int bad = 0;
        for (int i = t; i < 512; i += 64) {
            float v = (float)xb[i];
            if (!(v > -1e4f && v < 1e4f)) bad = 1;
        }
        unsigned long long m = __ballot(bad);
        if (t == 0) { sflag = (m != 0ull) ? 1 : 0; flag[0] = sflag; }
    }
    __syncthreads();
    int fp32 = sflag;
    for (int idx = t; idx < 256; idx += 256) {          // V1bd: k<128, h<2
        int k = idx >> 1, h = idx & 1;
        float s = 0.f;
        for (int c = 0; c < 64; ++c)
            s += ldin(w1bd, (size_t)k * 128 + h * 64 + c, fp32) * ldin(a1bd, h * 64 + c, fp32);
        V1bd[k * 2 + h] = s;
    }
    for (int idx = t; idx < 512; idx += 256) {          // V1rd: k<256, h<2
        int k = idx >> 1, h = idx & 1;
        float s = 0.f;
        for (int c = 0; c < 64; ++c)
            s += ldin(w1rd, (size_t)k * 128 + h * 64 + c, fp32) * ldin(a1rd, h * 64 + c, fp32);
        V1rd[k * 2 + h] = s;
    }
    for (int k = t; k < 128; k += 256) {                // V2bd
        float s = 0.f;
        for (int c = 0; c < 64; ++c)
            s += ldin(w2bd, (size_t)k * 64 + c, fp32) * ldin(a2bd, c, fp32);
        V2bd[k] = s;
    }
    for (int k = t; k < 128; k += 256) {                // V2rd
        float s = 0.f;
        for (int c = 0; c < 64; ++c)
            s += ldin(w2rd, (size_t)k * 64 + c, fp32) * ldin(a2rd, c, fp32);
        V2rd[k] = s;
    }
}

// All 4 weight transposes (W[K][N] -> Wt[N][K] bf16) in one dispatch (256 blocks).
__global__ __launch_bounds__(256) void prep_w4(const void* __restrict__ w1b, bf16_t* __restrict__ Wt1b,
                                               const void* __restrict__ w1r, bf16_t* __restrict__ Wt1r,
                                               const void* __restrict__ w2b, bf16_t* __restrict__ Wt2b,
                                               const void* __restrict__ w2r, bf16_t* __restrict__ Wt2r,
                                               const int* __restrict__ flag) {
    int fp32 = flag[0];
    int b = blockIdx.x;
    const void* W; bf16_t* Wt; int N, ks, base;
    if (b < 128)      { W = w1b; Wt = Wt1b; N = 128; ks = 8; base = 0;   }
    else if (b < 192) { W = w1r; Wt = Wt1r; N = 128; ks = 7; base = 128; }
    else if (b < 224) { W = w2b; Wt = Wt2b; N = 64;  ks = 7; base = 192; }
    else              { W = w2r; Wt = Wt2r; N = 64;  ks = 7; base = 224; }
    int idx = (b - base) * 256 + threadIdx.x;
    int K = 1 << ks;
    int n = idx >> ks, k = idx & (K - 1);
    if (n < N) Wt[idx] = (bf16_t)ldin(W, (size_t)k * N + n, fp32);
}

// Convert X[M][K] (flag dtype) -> bf16, fused with ad[m,h] = X[m,:] @ V[:,h].
template<int K>
__device__ __forceinline__ void cvt_body(const void* __restrict__ X,
                                         bf16_t* __restrict__ Xb,
                                         const float* __restrict__ V,
                                         float* __restrict__ ad,
                                         int M, int fp32, int blk) {
    constexpr int EPL = K / 64;
    int wid = (blk * 256 + (int)threadIdx.x) >> 6;
    int lane = threadIdx.x & 63;
    if (wid >= M) return;
    size_t base = (size_t)wid * K + lane * EPL;
    float x[EPL];
    if constexpr (EPL == 4) {
        if (fp32) { f32x4 t = *(const f32x4*)((const float*)X + base);
#pragma unroll
            for (int j = 0; j < 4; ++j) x[j] = t[j];
        } else { bf16x4 t = *(const bf16x4*)((const bf16_t*)X + base);
#pragma unroll
            for (int j = 0; j < 4; ++j) x[j] = (float)t[j];
        }
        bf16x4 o;
#pragma unroll
        for (int j = 0; j < 4; ++j) o[j] = (bf16_t)x[j];
        *(bf16x4*)(Xb + base) = o;
    } else {
        if (fp32) { f32x2 t = *(const f32x2*)((const float*)X + base);
#pragma unroll
            for (int j = 0; j < 2; ++j) x[j] = t[j];
        } else { bf16x2 t = *(const bf16x2*)((const bf16_t*)X + base);
#pragma unroll
            for (int j = 0; j < 2; ++j) x[j] = (float)t[j];
        }
        bf16x2 o;
#pragma unroll
        for (int j = 0; j < 2; ++j) o[j] = (bf16_t)x[j];
        *(bf16x2*)(Xb + base) = o;
    }
    float a0 = 0.f, a1 = 0.f;
#pragma unroll
    for (int j = 0; j < EPL; ++j) {
        int k = lane * EPL + j;
        a0 += x[j] * V[k * 2];
        a1 += x[j] * V[k * 2 + 1];
    }
    for (int off = 32; off; off >>= 1) {
        a0 += __shfl_down(a0, off);
        a1 += __shfl_down(a1, off);
    }
    if (lane == 0) { ad[(size_t)wid * 2] = a0; ad[(size_t)wid * 2 + 1] = a1; }
}

__global__ __launch_bounds__(256) void cvt2(const void* __restrict__ Xc, bf16_t* __restrict__ Xcb,
                                            const float* __restrict__ Vc, float* __restrict__ adc,
                                            const void* __restrict__ Xp, bf16_t* __restrict__ Xpb,
                                            const float* __restrict__ Vp, float* __restrict__ adp,
                                            int gC, const int* __restrict__ flag) {
    int fp32 = flag[0];
    if ((int)blockIdx.x < gC) cvt_body<256>(Xc, Xcb, Vc, adc, NCn, fp32, blockIdx.x);
    else                      cvt_body<128>(Xp, Xpb, Vp, adp, NPn, fp32, blockIdx.x - gC);
}

// ---------------- CSR build (both directions fused) --------------------------
__global__ __launch_bounds__(256) void zero2(int* __restrict__ a, int na,
                                             int* __restrict__ b, int nb) {
    int i = blockIdx.x * 256 + threadIdx.x;
    if (i < na) a[i] = 0;
    else if (i - na < nb) b[i - na] = 0;
}

__global__ __launch_bounds__(256) void hist2(const int* __restrict__ esrc,
                                             const int* __restrict__ edst,
                                             int* __restrict__ cntR,
                                             int* __restrict__ cntB, int E) {
    int e = blockIdx.x * 256 + threadIdx.x;
    if (e >= E) return;
    atomicAdd(&cntB[edst[e]], 1);
    atomicAdd(&cntR[esrc[e]], 1);
}

__global__ __launch_bounds__(256) void scan_blocks2(const int* __restrict__ cntB, int* __restrict__ rsB,
                                                    int* __restrict__ bsumB, int NB, int sbB,
                                                    const int* __restrict__ cntR, int* __restrict__ rsR,
                                                    int* __restrict__ bsumR, int NR) {
    const int* cnt; int* rs; int* bsum; int N; int b;
    if ((int)blockIdx.x < sbB) { cnt = cntB; rs = rsB; bsum = bsumB; N = NB; b = blockIdx.x; }
    else { cnt = cntR; rs = rsR; bsum = bsumR; N = NR; b = blockIdx.x - sbB; }
    int t = threadIdx.x;
    int base = b * 1024 + t * 4;
    int c[4];
#pragma unroll
    for (int k = 0; k < 4; ++k) { int i = base + k; c[k] = (i < N) ? cnt[i] : 0; }
    int tsum = c[0] + c[1] + c[2] + c[3];
    __shared__ int sd[256];
    sd[t] = tsum;
    __syncthreads();
    for (int off = 1; off < 256; off <<= 1) {
        int x = (t >= off) ? sd[t - off] : 0;
        __syncthreads();
        sd[t] += x;
        __syncthreads();
    }
    int run = sd[t] - tsum;
#pragma unroll
    for (int k = 0; k < 4; ++k) { int i = base + k; if (i < N) rs[i] = run; run += c[k]; }
    if (t == 255) bsum[b] = sd[255];
}

__global__ __launch_bounds__(128) void scan_bsum2(int* __restrict__ bsumB, int nbB,
                                                  int* __restrict__ bsumR, int nbR) {
    int* bsum = blockIdx.x ? bsumR : bsumB;
    int nb = blockIdx.x ? nbR : nbB;
    int t = threadIdx.x;
    __shared__ int sd[128];
    int v = (t < nb) ? bsum[t] : 0;
    sd[t] = v;
    __syncthreads();
    for (int off = 1; off < 128; off <<= 1) {
        int x = (t >= off) ? sd[t - off] : 0;
        __syncthreads();
        sd[t] += x;
        __syncthreads();
    }
    if (t < nb) bsum[t] = sd[t] - v;
}

// rs += carry; also seed the scatter cursors (cnt = rs) and the sentinels.
__global__ __launch_bounds__(256) void scan_add2(int* __restrict__ rsB, const int* __restrict__ bsumB,
                                                 int NB, int* __restrict__ cntB,
                                                 int* __restrict__ rsR, const int* __restrict__ bsumR,
                                                 int NR, int* __restrict__ cntR, int E) {
    int i = blockIdx.x * 256 + threadIdx.x;
    if (i < NB) { int v = rsB[i] + bsumB[i >> 10]; rsB[i] = v; cntB[i] = v; }
    if (i < NR) { int v = rsR[i] + bsumR[i >> 10]; rsR[i] = v; cntR[i] = v; }
    if (i == 0) { rsB[NB] = E; rsR[NR] = E; }
}

__global__ __launch_bounds__(256) void scatter2(const int* __restrict__ esrc,
                                                const int* __restrict__ edst,
                                                int* __restrict__ curB, int* __restrict__ curR,
                                                int* __restrict__ srcsB, int* __restrict__ dstsB,
                                                int* __restrict__ srcsR, int* __restrict__ dstsR,
                                                int E) {
    int e = blockIdx.x * 256 + threadIdx.x;
    if (e >= E) return;
    int s = esrc[e], d = edst[e];
    int pb = atomicAdd(&curB[d], 1);
    srcsB[pb] = s; dstsB[pb] = d;
    int pr = atomicAdd(&curR[s], 1);
    srcsR[pr] = d; dstsR[pr] = s;
}

// ---------------- LDS-free GEMM: C[M,N] = A[M,K] @ Wt[N,K]^T, all bf16 -------
// Fused att epilogue: by covers exactly one head's 64 columns, so each block
// computes the COMPLETE head dot as[r,h] = sum_c H[r,h*64+c]*att[h,c]
// from the fp32 accumulators (32 FMA + 4 shfl_xor rounds; no atomics).
template<int K>
__device__ __forceinline__ void gemm_body(const bf16_t* __restrict__ A,
                                          const bf16_t* __restrict__ Wt,
                                          bf16_t* __restrict__ C,
                                          const void* __restrict__ att,
                                          float* __restrict__ asout, int H,
                                          int M, int N, int fp32, int bx, int by) {
    const int w = threadIdx.x >> 6;
    const int lane = threadIdx.x & 63;
    const int lm = lane & 15;
    const int lq = lane >> 4;
    const int n0 = by * 64;
    const int r0 = bx * 128 + w * 32;
    int ra0 = r0 + lm;       if (ra0 > M - 1) ra0 = M - 1;
    int ra1 = r0 + 16 + lm;  if (ra1 > M - 1) ra1 = M - 1;
    const bf16_t* A0 = A + (size_t)ra0 * K + lq * 8;
    const bf16_t* A1 = A + (size_t)ra1 * K + lq * 8;
    const bf16_t* B0 = Wt + (size_t)(n0 + lm) * K + lq * 8;
    f32x4 acc[2][4] = {};
#pragma unroll
    for (int kt = 0; kt < K / 32; ++kt) {
        bf16x8 a0 = *(const bf16x8*)(A0 + kt * 32);
        bf16x8 a1 = *(const bf16x8*)(A1 + kt * 32);
#pragma unroll
        for (int nt = 0; nt < 4; ++nt) {
            bf16x8 b = *(const bf16x8*)(B0 + (size_t)nt * 16 * K + kt * 32);
            acc[0][nt] = __builtin_amdgcn_mfma_f32_16x16x32_bf16(a0, b, acc[0][nt], 0, 0, 0);
            acc[1][nt] = __builtin_amdgcn_mfma_f32_16x16x32_bf16(a1, b, acc[1][nt], 0, 0, 0);
        }
    }
#pragma unroll
    for (int rt = 0; rt < 2; ++rt) {
        const int crow0 = r0 + rt * 16 + lq * 4;
#pragma unroll
        for (int nt = 0; nt < 4; ++nt) {
            int col = n0 + nt * 16 + lm;
#pragma unroll
            for (int i = 0; i < 4; ++i) {
                int r = crow0 + i;
                if (r < M) C[(size_t)r * N + col] = (bf16_t)acc[rt][nt][i];
            }
        }
    }
    // ---- fused attention-dot epilogue ----
    float attv[4];
#pragma unroll
    for (int nt = 0; nt < 4; ++nt) attv[nt] = ldin(att, n0 + nt * 16 + lm, fp32);
    float part[2][4];
#pragma unroll
    for (int rt = 0; rt < 2; ++rt)
#pragma unroll
        for (int i = 0; i < 4; ++i) {
            float s = 0.f;
#pragma unroll
            for (int nt = 0; nt < 4; ++nt) s += acc[rt][nt][i] * attv[nt];
            part[rt][i] = s;
        }
#pragma unroll
    for (int off = 1; off < 16; off <<= 1)
#pragma unroll
        for (int rt = 0; rt < 2; ++rt)
#pragma unroll
            for (int i = 0; i < 4; ++i)
                part[rt][i] += __shfl_xor(part[rt][i], off);
    if (lm == 0) {
#pragma unroll
        for (int rt = 0; rt < 2; ++rt)
#pragma unroll
            for (int i = 0; i < 4; ++i) {
                int r = r0 + rt * 16 + lq * 4 + i;
                if (r < M) asout[(size_t)r * H + by] = part[rt][i];
            }
    }
}

// L1: customers (K=256) in blocks [0,gmC), products (K=128) in [gmC, gmC+gmP).
__global__ __launch_bounds__(256) void gemm_l1(const bf16_t* __restrict__ xcb, const bf16_t* __restrict__ Wt1b,
                                               bf16_t* __restrict__ Hc, const void* __restrict__ a1b, float* __restrict__ as_b,
                                               const bf16_t* __restrict__ xpb, const bf16_t* __restrict__ Wt1r,
                                               bf16_t* __restrict__ Hp, const void* __restrict__ a1r, float* __restrict__ as_r,
                                               int gmC, const int* __restrict__ flag) {
    int fp32 = flag[0];
    if ((int)blockIdx.x < gmC)
        gemm_body<256>(xcb, Wt1b, Hc, a1b, as_b, 2, NCn, 128, fp32, blockIdx.x, blockIdx.y);
    else
        gemm_body<128>(xpb, Wt1r, Hp, a1r, as_r, 2, NPn, 128, fp32, blockIdx.x - gmC, blockIdx.y);
}

// L2: both K=128, N=64, single head.
__global__ __launch_bounds__(256) void gemm_l2(const bf16_t* __restrict__ c1, const bf16_t* __restrict__ Wt2b,
                                               bf16_t* __restrict__ Hc2, const void* __restrict__ a2b, float* __restrict__ as2c,
                                               const bf16_t* __restrict__ p1, const bf16_t* __restrict__ Wt2r,
                                               bf16_t* __restrict__ Hp2, const void* __restrict__ a2r, float* __restrict__ as2p,
                                               int gmC, const int* __restrict__ flag) {
    int fp32 = flag[0];
    if ((int)blockIdx.x < gmC)
        gemm_body<128>(c1, Wt2b, Hc2, a2b, as2c, 1, NCn, 64, fp32, blockIdx.x, 0);
    else
        gemm_body<128>(p1, Wt2r, Hp2, a2r, as2p, 1, NPn, 64, fp32, blockIdx.x - gmC, 0);
}

// ---------------- edge-parallel packed records, both dirs --------------------
// H==2: pk[j] = {byte_off = src<<8, e0, e1, 0} (16 B).  H==1: {src<<7, e} (8 B).
// Moves ALL per-edge score math + src indexing out of the wave-serial
// aggregate loop; aggregate then does ONE uniform load per edge.
template<int H>
__global__ __launch_bounds__(256) void edge_pk2(const int* __restrict__ srcsB,
                                                const int* __restrict__ dstsB,
                                                const float* __restrict__ asB,
                                                const float* __restrict__ adB,
                                                float* __restrict__ pkB,
                                                const int* __restrict__ srcsR,
                                                const int* __restrict__ dstsR,
                                                const float* __restrict__ asR,
                                                const float* __restrict__ adR,
                                                float* __restrict__ pkR, int E) {
    int i = blockIdx.x * 256 + threadIdx.x;
    const int *srcs, *dsts; const float *as_, *ad_; float* pk; int j;
    if (i < E) { j = i; srcs = srcsB; dsts = dstsB; as_ = asB; ad_ = adB; pk = pkB; }
    else {
        j = i - E;
        if (j >= E) return;
        srcs = srcsR; dsts = dstsR; as_ = asR; ad_ = adR; pk = pkR;
    }
    int s = srcs[j], d = dsts[j];
    if constexpr (H == 2) {
        f32x2 a = *(const f32x2*)(as_ + 2 * (size_t)s);
        f32x2 b = *(const f32x2*)(ad_ + 2 * (size_t)d);
        float v0 = a[0] + b[0]; v0 = v0 > 0.f ? v0 : 0.2f * v0;
        float v1 = a[1] + b[1]; v1 = v1 > 0.f ? v1 : 0.2f * v1;
        f32x4 o;
        o[0] = __uint_as_float((unsigned)s << 8);
        o[1] = __expf(fminf(v0, 60.f));
        o[2] = __expf(fminf(v1, 60.f));
        o[3] = 0.f;
        *(f32x4*)(pk + 4 * (size_t)j) = o;
    } else {
        float v = as_[s] + ad_[d];
        v = v > 0.f ? v : 0.2f * v;
        f32x2 o;
        o[0] = __uint_as_float((unsigned)s << 7);
        o[1] = __expf(fminf(v, 60.f));
        *(f32x2*)(pk + 2 * (size_t)j) = o;
    }
}

// ---------------- fused segment-softmax + aggregate, both dirs ---------------
// One wave per destination, SERIAL edge loop (proven structure): 64 lanes own
// one full H-row (perfect coalescing). Per edge: one uniform dwordx4/dwordx2
// packed load + 32-bit offset add onto a hoisted per-lane base + gather +
// cndmask + 2 cvt + 2 fma + den add. Denominator folded into the loop;
// normalize in epilogue. MODE 0: relu + bf16 + fused ad2 = relu(out) . V2.
template<int HD, int MODE>
__global__ __launch_bounds__(256) void aggregate2(
        const int* __restrict__ rsB, const float* __restrict__ pkB,
        const bf16_t* __restrict__ HmB, const void* __restrict__ biasB,
        const float* __restrict__ V2B, float* __restrict__ ad2B,
        void* __restrict__ outB, size_t obaseB, int NdB,
        const int* __restrict__ rsR, const float* __restrict__ pkR,
        const bf16_t* __restrict__ HmR, const void* __restrict__ biasR,
        const float* __restrict__ V2R, float* __restrict__ ad2R,
        void* __restrict__ outR, size_t obaseR, int NdR,
        const int* __restrict__ flag) {
    constexpr int NH = HD / 64;       // heads: 2 (layer1) or 1 (layer2)
    int gw = (blockIdx.x * 256 + threadIdx.x) >> 6;
    int lane = threadIdx.x & 63;
    const int* rs; const float* pk; const bf16_t* Hm;
    const void* bias; const float* V2; float* ad2; void* outb; size_t obase; int wid;
    if (gw < NdB) {
        wid = gw;
        rs = rsB; pk = pkB; Hm = HmB; bias = biasB;
        V2 = V2B; ad2 = ad2B; outb = outB; obase = obaseB;
    } else {
        wid = gw - NdB;
        if (wid >= NdR) return;
        rs = rsR; pk = pkR; Hm = HmR; bias = biasR;
        V2 = V2R; ad2 = ad2R; outb = outR; obase = obaseR;
    }
    int start = rs[wid], end = rs[wid + 1];
    int fp32 = flag[0];
    const int hsel = lane >> 5;       // which head this lane's channels use

    float den = 0.f, acc0 = 0.f, acc1 = 0.f;
    if constexpr (NH == 2) {
        const char* Hlane = (const char*)Hm + 4 * lane;   // 2 channels * 2B
        const f32x4* pkv = (const f32x4*)pk;
#pragma unroll 4
        for (int j = start; j < end; ++j) {
            f32x4 e = pkv[j];                              // wave-uniform
            unsigned off = __float_as_uint(e[0]);
            float eh = hsel ? e[2] : e[1];
            den += eh;
            bf16x2 hv = *(const bf16x2*)(Hlane + off);
            acc0 += (float)hv[0] * eh;
            acc1 += (float)hv[1] * eh;
        }
    } else {
        const char* Hlane = (const char*)Hm + 2 * lane;   // 1 channel * 2B
        const f32x2* pkv = (const f32x2*)pk;
#pragma unroll 4
        for (int j = start; j < end; ++j) {
            f32x2 e = pkv[j];                              // wave-uniform
            unsigned off = __float_as_uint(e[0]);
            float eh = e[1];
            den += eh;
            acc0 += (float)(*(const bf16_t*)(Hlane + off)) * eh;
        }
    }
    float inv = 1.f / (den + 1e-16f);

    if constexpr (MODE == 0) {
        int c0 = 2 * lane;
        float o0 = fmaxf(acc0 * inv + ldin(bias, c0, fp32), 0.f);
        float o1 = fmaxf(acc1 * inv + ldin(bias, c0 + 1, fp32), 0.f);
        bf16x2 ov;
        ov[0] = (bf16_t)o0;
        ov[1] = (bf16_t)o1;
        *(bf16x2*)((bf16_t*)outb + (size_t)wid * 128 + c0) = ov;
        float pp = o0 * V2[c0] + o1 * V2[c0 + 1];
        for (int off = 32; off; off >>= 1) pp += __shfl_down(pp, off);
        if (lane == 0) ad2[wid] = pp;
    } else {
        float o = acc0 * inv + ldin(bias, lane, fp32);
        size_t oi = obase + (size_t)wid * 64 + lane;
        if (fp32) ((float*)outb)[oi] = o;
        else      ((bf16_t*)outb)[oi] = (bf16_t)o;
    }
}

extern "C" void kernel_launch(void* const* d_in, const int* in_sizes, int n_in,
                              void* d_out, int out_size, void* d_ws, size_t ws_size,
                              hipStream_t stream) {
    const void* xc = d_in[0];
    const void* xp = d_in[1];
    const int* esrc = (const int*)d_in[2];   // customer ids
    const int* edst = (const int*)d_in[3];   // product ids
    const void* w1b_src = d_in[4];
    const void* w1b_dst = d_in[5];
    const void* a1b_src = d_in[6];
    const void* a1b_dst = d_in[7];
    const void* b1b     = d_in[8];
    const void* w1r_src = d_in[9];
    const void* w1r_dst = d_in[10];
    const void* a1r_src = d_in[11];
    const void* a1r_dst = d_in[12];
    const void* b1r     = d_in[13];
    const void* w2b_src = d_in[14];
    const void* w2b_dst = d_in[15];
    const void* a2b_src = d_in[16];
    const void* a2b_dst = d_in[17];
    const void* b2b     = d_in[18];
    const void* w2r_src = d_in[19];
    const void* w2r_dst = d_in[20];
    const void* a2r_src = d_in[21];
    const void* a2r_dst = d_in[22];
    const void* b2r     = d_in[23];

    // -------- workspace layout: NO aliasing (~189 MB, ws proven >= 199 MB) ----
    char* p = (char*)d_ws;
    auto alloc = [&](size_t nbytes) {
        char* r = p;
        p += (nbytes + 255) & ~(size_t)255;
        return r;
    };
    int* flag   = (int*)alloc(256);
    float* V1bd = (float*)alloc(256 * 4);
    float* V1rd = (float*)alloc(512 * 4);
    float* V2bd = (float*)alloc(128 * 4);
    float* V2rd = (float*)alloc(128 * 4);
    bf16_t* Wt1b = (bf16_t*)alloc(128 * 256 * 2);
    bf16_t* Wt1r = (bf16_t*)alloc(128 * 128 * 2);
    bf16_t* Wt2b = (bf16_t*)alloc(64 * 128 * 2);
    bf16_t* Wt2r = (bf16_t*)alloc(64 * 128 * 2);
    float* as_b = (float*)alloc((size_t)NCn * 2 * 4);   // L1-b src scores (customers)
    float* as_r = (float*)alloc((size_t)NPn * 2 * 4);   // L1-r src scores (products)
    float* as2_c = (float*)alloc((size_t)NCn * 4);      // L2-b src scores (customers)
    float* as2_p = (float*)alloc((size_t)NPn * 4);      // L2-r src scores (products)
    float* ad_b = (float*)alloc((size_t)NPn * 2 * 4);
    float* ad_r = (float*)alloc((size_t)NCn * 2 * 4);
    float* ad2_b = (float*)alloc((size_t)NPn * 4);
    float* ad2_r = (float*)alloc((size_t)NCn * 4);
    int* rsB    = (int*)alloc((size_t)(NPn + 1) * 4);
    int* rsR    = (int*)alloc((size_t)(NCn + 1) * 4);
    int* srcsB  = (int*)alloc((size_t)NE * 4);
    int* srcsR  = (int*)alloc((size_t)NE * 4);
    int* dstsB  = (int*)alloc((size_t)NE * 4);
    int* dstsR  = (int*)alloc((size_t)NE * 4);
    float* pkB  = (float*)alloc((size_t)NE * 16);
    float* pkR  = (float*)alloc((size_t)NE * 16);
    int* cntB   = (int*)alloc((size_t)NPn * 4);
    int* cntR   = (int*)alloc((size_t)NCn * 4);
    int* bsumB  = (int*)alloc(128 * 4);
    int* bsumR  = (int*)alloc(128 * 4);
    bf16_t* xcb = (bf16_t*)alloc((size_t)NCn * 256 * 2);
    bf16_t* xpb = (bf16_t*)alloc((size_t)NPn * 128 * 2);
    bf16_t* Hc  = (bf16_t*)alloc((size_t)NCn * 128 * 2);
    bf16_t* Hp  = (bf16_t*)alloc((size_t)NPn * 128 * 2);
    bf16_t* c1  = (bf16_t*)alloc((size_t)NCn * 128 * 2);
    bf16_t* p1  = (bf16_t*)alloc((size_t)NPn * 128 * 2);
    bf16_t* Hc2 = (bf16_t*)alloc((size_t)NCn * 64 * 2);
    bf16_t* Hp2 = (bf16_t*)alloc((size_t)NPn * 64 * 2);

    const dim3 blk(256);
    const int gE = (NE + 255) / 256;
    const int g2E = (2 * NE + 255) / 256;
    const int sbP = (NPn + 1023) / 1024;
    const int sbR = (NCn + 1023) / 1024;
    const int gmC = (NCn + 127) / 128;
    const int gmP = (NPn + 127) / 128;
    const int gNC = (NCn + 255) / 256;
    const int gBoth = (NPn + NCn + 255) / 256;
    const int gAgg = (NPn + NCn + 3) / 4;      // 1 wave per destination, both dirs
    const int gCvtC = (NCn + 3) / 4;
    const int gCvtP = (NPn + 3) / 4;

    prep_meta<<<1, 256, 0, stream>>>(xc, flag, w1b_dst, a1b_dst, w1r_dst, a1r_dst,
                                     w2b_dst, a2b_dst, w2r_dst, a2r_dst,
                                     V1bd, V1rd, V2bd, V2rd);
    prep_w4<<<256, blk, 0, stream>>>(w1b_src, Wt1b, w1r_src, Wt1r,
                                     w2b_src, Wt2b, w2r_src, Wt2r, flag);

    // -------- CSR build, both directions fused --------
    zero2<<<gBoth, blk, 0, stream>>>(cntB, NPn, cntR, NCn);
    hist2<<<gE, blk, 0, stream>>>(esrc, edst, cntR, cntB, NE);
    scan_blocks2<<<sbP + sbR, blk, 0, stream>>>(cntB, rsB, bsumB, NPn, sbP,
                                                cntR, rsR, bsumR, NCn);
    scan_bsum2<<<2, 128, 0, stream>>>(bsumB, sbP, bsumR, sbR);
    scan_add2<<<gNC, blk, 0, stream>>>(rsB, bsumB, NPn, cntB, rsR, bsumR, NCn, cntR, NE);
    scatter2<<<gE, blk, 0, stream>>>(esrc, edst, cntB, cntR, srcsB, dstsB, srcsR, dstsR, NE);

    // -------- convert inputs to bf16 + fused L1 dst scores (one dispatch) ----
    cvt2<<<gCvtC + gCvtP, blk, 0, stream>>>(xc, xcb, V1rd, ad_r,
                                            xp, xpb, V1bd, ad_b, gCvtC, flag);

    // -------- layer 1 src projections (+ fused as = H . att_src) -------------
    gemm_l1<<<dim3(gmC + gmP, 2), blk, 0, stream>>>(xcb, Wt1b, Hc, a1b_src, as_b,
                                                    xpb, Wt1r, Hp, a1r_src, as_r,
                                                    gmC, flag);

    // -------- L1 packed edge records + aggregate, both dirs ------------------
    edge_pk2<2><<<g2E, blk, 0, stream>>>(srcsB, dstsB, as_b, ad_b, pkB,
                                         srcsR, dstsR, as_r, ad_r, pkR, NE);
    aggregate2<128, 0><<<gAgg, blk, 0, stream>>>(
        rsB, pkB, Hc, b1b, V2bd, ad2_b, p1, 0, NPn,
        rsR, pkR, Hp, b1r, V2rd, ad2_r, c1, 0, NCn, flag);

    // -------- layer 2 src projections (+ fused as2 = H2 . att_src) -----------
    gemm_l2<<<dim3(gmC + gmP, 1), blk, 0, stream>>>(c1, Wt2b, Hc2, a2b_src, as2_c,
                                                    p1, Wt2r, Hp2, a2r_src, as2_p,
                                                    gmC, flag);

    // -------- L2 packed edge records + final aggregate -----------------------
    edge_pk2<1><<<g2E, blk, 0, stream>>>(srcsB, dstsB, as2_c, ad2_b, pkB,
                                         srcsR, dstsR, as2_p, ad2_r, pkR, NE);
    aggregate2<64, 1><<<gAgg, blk, 0, stream>>>(
        rsB, pkB, Hc2, b2b, nullptr, nullptr, d_out, (size_t)NCn * 64, NPn,
        rsR, pkR, Hp2, b2r, nullptr, nullptr, d_out, 0, NCn, flag);
}